// Round 11
// baseline (4242.122 us; speedup 1.0000x reference)
//
#include <hip/hip_runtime.h>
#include <stdint.h>

#define TPB 256
#define TPS 1024          // threads per sort block

// Problem constants
constexpr int BN   = 64;          // batch
constexpr int CCH  = 3;           // channels
constexpr int HWS  = 262144;      // H*W
constexpr int LOG_HW = 18;
constexpr int NPS  = 786432;      // C*H*W per sample
constexpr int KSEL = 196608;      // K_UPPER
constexpr int KCAP = 200704;      // KSEL + slack for boundary duplicates
constexpr int NB_T = 32;          // blocks/sample for thrA scan
constexpr int CH_T = NPS / NB_T;  // 24576
constexpr int NB_C = 64;          // blocks/sample for compaction/fill scans
constexpr int CH_C = NPS / NB_C;  // 12288
constexpr int WCH  = CH_C / 4;    // 3072 elements per wave subrange
constexpr int NB_S = 8;           // blocks/sample for sort passes
constexpr int CH_S = KCAP / NB_S; // 25088
constexpr int TILE = 4096;        // records per sort tile (TPS * 4)
constexpr int NBINS = 2048;       // threshold-refinement bins
constexpr int SUB  = 8;           // sub-blocks per (b,c) in mnmx
constexpr int NFB  = 49;          // fill bins: KCAP / 4096
constexpr int ACAP = 262144;      // append capacity per sample (boundary bin ~37K expected)

// native vector type for nontemporal builtins (HIP uint4 is a class type)
typedef unsigned u32x4 __attribute__((ext_vector_type(4)));

// ws layout (u32 offsets)
constexpr int WS_MN   = 0;        // f32[192]
constexpr int WS_MX   = 192;      // f32[192]
constexpr int WS_V1   = 384;      // u32[64]
constexpr int WS_B1   = 448;      // u32[64]
constexpr int WS_V2   = 512;      // u32[64]
constexpr int WS_GS   = 576;      // u32[64] inclusive key threshold G*
constexpr int WS_KP   = 640;      // u32[64] compacted count per sample
constexpr int WS_S0   = 704;      // u32[64] selected in ch0
constexpr int WS_S01  = 768;      // u32[64] selected in ch0+ch1
constexpr int WS_CNT  = 832;                      // u32[64][256] cntLess per wave-range
constexpr int WS_COFF = WS_CNT + BN * 256;        // 17216
constexpr int WS_MNP  = WS_COFF + BN * 256;       // 33600 ; f32[1536]
constexpr int WS_MXP  = WS_MNP + BN * CCH * SUB;  // 35136 ; f32[1536]
// ---- zeroed-each-launch region starts here ----
constexpr int WS_CNT2 = WS_MXP + BN * CCH * SUB;  // 36672 ; u32[64][256] boundary counts
constexpr int WS_ACNT = WS_CNT2 + BN * 256;       // 53056 ; u32[64] append counters
constexpr int WS_CHC  = WS_ACNT + BN;             // 53120 ; u32[64][4] channel-selected counts
constexpr int WS_THA  = WS_CHC + BN * 4;          // 53376
constexpr int WS_THB  = WS_THA + BN * NBINS;      // 184448
constexpr int WS_H0   = WS_THB + BN * NBINS;      // 315520 ; u32[64][256][NB_S]
constexpr int WS_H1   = WS_H0 + BN * 256 * NB_S;
constexpr int WS_H2   = WS_H1 + BN * 256 * NB_S;
constexpr int WS_H3   = WS_H2 + BN * 256 * NB_S;
constexpr int WS_HF   = WS_H3 + BN * 256 * NB_S;  // u32[64][64][NB_S] fill-bin hist
constexpr size_t WS_FIX_END = (size_t)WS_HF + (size_t)BN * 64 * NB_S;   // 872576 words
constexpr size_t RECW = (size_t)BN * KCAP * 2;   // words per uint2 record buffer
constexpr size_t WS_NEEDED_BYTES = (WS_FIX_END + 2 * RECW) * 4;   // ~209 MB (proven-safe)
static_assert((size_t)BN * ACAP <= RECW, "append scratch must fit in R2");

// ---------------- threefry2x32 (JAX-exact, partitionable stream) ----------------
__device__ __forceinline__ unsigned rotl32(unsigned x, int r) { return (x << r) | (x >> (32 - r)); }

__device__ __forceinline__ void tf4(unsigned& x0, unsigned& x1, int a, int b, int c, int d) {
  x0 += x1; x1 = rotl32(x1, a); x1 ^= x0;
  x0 += x1; x1 = rotl32(x1, b); x1 ^= x0;
  x0 += x1; x1 = rotl32(x1, c); x1 ^= x0;
  x0 += x1; x1 = rotl32(x1, d); x1 ^= x0;
}

__device__ __forceinline__ void threefry2x32(unsigned k0, unsigned k1, unsigned c0, unsigned c1,
                                             unsigned& o0, unsigned& o1) {
  const unsigned ks2 = k0 ^ k1 ^ 0x1BD11BDAu;
  unsigned x0 = c0 + k0, x1 = c1 + k1;
  tf4(x0, x1, 13, 15, 26, 6);  x0 += k1;  x1 += ks2 + 1u;
  tf4(x0, x1, 17, 29, 16, 24); x0 += ks2; x1 += k0 + 2u;
  tf4(x0, x1, 13, 15, 26, 6);  x0 += k0;  x1 += k1 + 3u;
  tf4(x0, x1, 17, 29, 16, 24); x0 += k1;  x1 += ks2 + 4u;
  tf4(x0, x1, 13, 15, 26, 6);  x0 += ks2; x1 += k0 + 5u;
  o0 = x0; o1 = x1;
}

// ---------------- kernels ----------------
__global__ __launch_bounds__(TPB) void k_zero(unsigned* __restrict__ p, int n) {
  int i = blockIdx.x * TPB + threadIdx.x;
  if (i < n) p[i] = 0u;
}

// per-(b,c) min/max partials (excluding channel's last element) — read-only
__global__ __launch_bounds__(TPB) void k_mnmx(const float4* __restrict__ x,
                                              unsigned* __restrict__ ws) {
  __shared__ float smn[TPB], smx[TPB];
  const int g = blockIdx.x;            // bc*SUB + sub
  const int bc = g / SUB, sub = g - bc * SUB;
  const int Q4 = HWS / 4 / SUB;
  const size_t base4 = (size_t)bc * (HWS / 4) + (size_t)sub * Q4;
  const bool last = (sub == SUB - 1);
  const int tid = threadIdx.x;
  float lo = 3.4e38f, hi = -3.4e38f;
  for (int i = tid; i < Q4; i += TPB) {
    float4 v = x[base4 + i];
    if (last && i == Q4 - 1) {         // exclude final element of the channel
      lo = fminf(lo, fminf(fminf(v.x, v.y), v.z));
      hi = fmaxf(hi, fmaxf(fmaxf(v.x, v.y), v.z));
    } else {
      lo = fminf(lo, fminf(fminf(v.x, v.y), fminf(v.z, v.w)));
      hi = fmaxf(hi, fmaxf(fmaxf(v.x, v.y), fmaxf(v.z, v.w)));
    }
  }
  smn[tid] = lo; smx[tid] = hi; __syncthreads();
  for (int s = TPB / 2; s > 0; s >>= 1) {
    if (tid < s) { smn[tid] = fminf(smn[tid], smn[tid + s]); smx[tid] = fmaxf(smx[tid], smx[tid + s]); }
    __syncthreads();
  }
  if (tid == 0) {
    ((float*)(ws + WS_MNP))[g] = smn[0];
    ((float*)(ws + WS_MXP))[g] = smx[0];
  }
}

__global__ __launch_bounds__(TPB) void k_mnfin(unsigned* __restrict__ ws) {
  const int t = threadIdx.x;
  if (t < BN * CCH) {
    const float* mnp = (const float*)(ws + WS_MNP);
    const float* mxp = (const float*)(ws + WS_MXP);
    float lo = 3.4e38f, hi = -3.4e38f;
    for (int s = 0; s < SUB; ++s) {
      lo = fminf(lo, mnp[t * SUB + s]);
      hi = fmaxf(hi, mxp[t * SUB + s]);
    }
    ((float*)(ws + WS_MN))[t] = lo;
    ((float*)(ws + WS_MX))[t] = hi;
  }
}

__global__ __launch_bounds__(TPB) void k_thrA(const unsigned* __restrict__ gb, unsigned* __restrict__ hist) {
  __shared__ unsigned h[NBINS];
  const int b = blockIdx.y, blk = blockIdx.x, tid = threadIdx.x;
  for (int v = tid; v < NBINS; v += TPB) h[v] = 0u;
  __syncthreads();
  const uint4* g4 = (const uint4*)(gb + (size_t)b * NPS + (size_t)blk * CH_T);
  for (int i = tid; i < CH_T / 4; i += TPB) {
    uint4 v = g4[i];
    atomicAdd(&h[(v.x & 0x7FFFFFFFu) >> 21], 1u);
    atomicAdd(&h[(v.y & 0x7FFFFFFFu) >> 21], 1u);
    atomicAdd(&h[(v.z & 0x7FFFFFFFu) >> 21], 1u);
    atomicAdd(&h[(v.w & 0x7FFFFFFFu) >> 21], 1u);
  }
  __syncthreads();
  unsigned* gh = hist + (size_t)b * NBINS;
  for (int v = tid; v < NBINS; v += TPB) if (h[v]) atomicAdd(&gh[v], h[v]);
}

// Fused second refinement + range-count pass (replaces thrB AND ccount):
// per-wave-range count(top < V1), per-channel cntLess totals,
// mid-11 histogram of top==V1 matches, wave-aggregated append of (range|ch|mid).
__global__ __launch_bounds__(TPB) void k_thrBC(const unsigned* __restrict__ gb,
                                               unsigned* __restrict__ hist,
                                               unsigned* __restrict__ app,
                                               unsigned* __restrict__ ws) {
  __shared__ unsigned h[NBINS];
  __shared__ unsigned chs[3];
  const int bid = blockIdx.x;
  const int b = bid & 63, blk = bid >> 6, tid = threadIdx.x;
  const int lane = tid & 63, wv = tid >> 6;
  const unsigned long long ltm = (1ull << lane) - 1ull;
  for (int v = tid; v < NBINS; v += TPB) h[v] = 0u;
  if (tid < 3) chs[tid] = 0u;
  __syncthreads();
  const unsigned V1 = ws[WS_V1 + b];
  const unsigned rangeId = (unsigned)(blk * 4 + wv);
  const uint4* g4 = (const uint4*)(gb + (size_t)b * NPS + (size_t)blk * CH_C) + wv * (WCH / 4);
  const unsigned e0 = (unsigned)blk * CH_C + (unsigned)wv * WCH;
  unsigned* ap = app + (size_t)b * ACAP;
  unsigned cntLess = 0, cc0 = 0, cc1 = 0, cc2 = 0;
  for (int it = 0; it < WCH / 256; ++it) {
    const uint4 v = g4[it * 64 + lane];
    const unsigned e = e0 + (unsigned)it * 256u + (unsigned)lane * 4u;
    const unsigned k[4] = { v.x & 0x7FFFFFFFu, v.y & 0x7FFFFFFFu, v.z & 0x7FFFFFFFu, v.w & 0x7FFFFFFFu };
#pragma unroll
    for (int c = 0; c < 4; ++c) {
      const unsigned top = k[c] >> 21;
      const bool isEq = (top == V1);
      if (top < V1) {
        ++cntLess;
        const unsigned ch = (e + (unsigned)c) >> LOG_HW;
        if (ch == 0) ++cc0; else if (ch == 1) ++cc1; else ++cc2;
      } else if (isEq) {
        atomicAdd(&h[(k[c] >> 10) & 2047u], 1u);
      }
      // wave-aggregated append of boundary-bin matches
      unsigned long long m = __ballot(isEq);
      if (m) {
        const int ldr = __ffsll((unsigned long long)m) - 1;
        unsigned base = 0;
        if (lane == ldr) base = atomicAdd(&ws[WS_ACNT + b], (unsigned)__popcll(m));
        base = __shfl(base, ldr, 64);
        if (isEq) {
          const unsigned ai = base + (unsigned)__popcll(m & ltm);
          if (ai < (unsigned)ACAP) {
            const unsigned ch = (e + (unsigned)c) >> LOG_HW;
            ap[ai] = (rangeId << 13) | (ch << 11) | ((k[c] >> 10) & 2047u);
          }
        }
      }
    }
  }
  for (int off = 32; off >= 1; off >>= 1) cntLess += __shfl_down(cntLess, off, 64);
  if (lane == 0) ws[WS_CNT + b * 256 + rangeId] = cntLess;
  if (cc0) atomicAdd(&chs[0], cc0);
  if (cc1) atomicAdd(&chs[1], cc1);
  if (cc2) atomicAdd(&chs[2], cc2);
  __syncthreads();
  if (tid < 3 && chs[tid]) atomicAdd(&ws[WS_CHC + b * 4 + tid], chs[tid]);
  unsigned* gh = hist + (size_t)b * NBINS;
  for (int v = tid; v < NBINS; v += TPB) if (h[v]) atomicAdd(&gh[v], h[v]);
}

// mode 0: top 10 bits -> V1, B1 ; mode 1: mid 11 bits -> V2, G* (21-bit prefix), Kp
__global__ __launch_bounds__(TPB) void k_find(const unsigned* __restrict__ hist,
                                              unsigned* __restrict__ ws, int mode) {
  __shared__ unsigned part[TPB];
  const int b = blockIdx.x, tid = threadIdx.x;
  const unsigned* h = hist + (size_t)b * NBINS;
  const int per = NBINS / TPB;
  const unsigned Kt = (mode == 0) ? (unsigned)KSEL : (unsigned)KSEL - ws[WS_B1 + b];
  unsigned vals[8];
  unsigned s = 0;
  for (int j = 0; j < per; ++j) { vals[j] = h[tid * per + j]; s += vals[j]; }
  part[tid] = s; __syncthreads();
  for (int off = 1; off < TPB; off <<= 1) {
    unsigned t = (tid >= off) ? part[tid - off] : 0u;
    __syncthreads(); part[tid] += t; __syncthreads();
  }
  unsigned run = part[tid] - s;
  for (int j = 0; j < per; ++j) {
    const unsigned lo = run, c = vals[j];
    run += c;
    if (lo < Kt && Kt <= run) {
      const unsigned v = (unsigned)(tid * per + j);
      if (mode == 0) {
        ws[WS_V1 + b] = v; ws[WS_B1 + b] = lo;
      } else {
        ws[WS_V2 + b] = v;
        const unsigned T22 = (ws[WS_V1 + b] << 11) | v;
        ws[WS_GS + b] = (T22 << 10) | 1023u;        // inclusive 31-bit threshold
        unsigned kp = ws[WS_B1 + b] + lo + c;       // countLess + countEq
        if (kp > (unsigned)KCAP) kp = (unsigned)KCAP;
        ws[WS_KP + b] = kp;
      }
    }
  }
}

// count boundary-bin matches with mid <= V2 per wave-range + per channel (tiny)
__global__ __launch_bounds__(TPB) void k_cc2(const unsigned* __restrict__ app,
                                             unsigned* __restrict__ ws) {
  __shared__ unsigned loc[256];
  __shared__ unsigned lch[3];
  const int b = blockIdx.x, tid = threadIdx.x;
  for (int j = tid; j < 256; j += TPB) loc[j] = 0u;
  if (tid < 3) lch[tid] = 0u;
  __syncthreads();
  const unsigned n = min(ws[WS_ACNT + b], (unsigned)ACAP);
  const unsigned V2 = ws[WS_V2 + b];
  const unsigned* ap = app + (size_t)b * ACAP;
  for (unsigned i = tid; i < n; i += TPB) {
    const unsigned e = ap[i];
    if ((e & 2047u) <= V2) {
      atomicAdd(&loc[e >> 13], 1u);
      atomicAdd(&lch[(e >> 11) & 3u], 1u);
    }
  }
  __syncthreads();
  for (int j = tid; j < 256; j += TPB) ws[WS_CNT2 + b * 256 + j] = loc[j];
  if (tid < 3 && lch[tid]) atomicAdd(&ws[WS_CHC + b * 4 + tid], lch[tid]);
}

// scan 256 per-wave-range totals (cntLess + cnt2) -> COFF ; channel boundaries
__global__ __launch_bounds__(TPB) void k_cscan(unsigned* __restrict__ ws) {
  __shared__ unsigned wsum[4];
  const int b = blockIdx.x, tid = threadIdx.x;
  const int lane = tid & 63, wv = tid >> 6;
  const unsigned cnt = ws[WS_CNT + b * 256 + tid] + ws[WS_CNT2 + b * 256 + tid];
  unsigned incl = cnt;
  for (int off = 1; off < 64; off <<= 1) {
    unsigned t = __shfl_up(incl, off, 64);
    if (lane >= off) incl += t;
  }
  if (lane == 63) wsum[wv] = incl;
  __syncthreads();
  unsigned wpre = 0;
  for (int w = 0; w < wv; ++w) wpre += wsum[w];
  ws[WS_COFF + b * 256 + tid] = incl - cnt + wpre;
  if (tid == 0) {
    const unsigned s0 = ws[WS_CHC + b * 4 + 0];
    ws[WS_S0 + b] = s0;
    ws[WS_S01 + b] = s0 + ws[WS_CHC + b * 4 + 1];
  }
}

// Index-ordered compaction (wave-independent) -> 4B keys, fused pass-1 hist H0.
__global__ __launch_bounds__(TPB) void k_cscatter(const unsigned* __restrict__ gb,
                                                  const unsigned* __restrict__ ws,
                                                  unsigned* __restrict__ keyArr,
                                                  unsigned* __restrict__ H0) {
  __shared__ unsigned h2[256 * NB_S];   // 8 KB
  const int bid = blockIdx.x;
  const int b = bid & 63, blk = bid >> 6, tid = threadIdx.x;
  const int lane = tid & 63, wv = tid >> 6;
  for (int e = tid; e < 256 * NB_S; e += TPB) h2[e] = 0u;
  __syncthreads();
  const unsigned G = ws[WS_GS + b];
  unsigned base = ws[WS_COFF + b * 256 + blk * 4 + wv];
  const uint4* g4 = (const uint4*)(gb + (size_t)b * NPS + (size_t)blk * CH_C) + wv * (WCH / 4);
  unsigned* ka = keyArr + (size_t)b * KCAP;
  for (int it = 0; it < WCH / 256; ++it) {
    const uint4 v = g4[it * 64 + lane];
    unsigned k[4] = { v.x & 0x7FFFFFFFu, v.y & 0x7FFFFFFFu, v.z & 0x7FFFFFFFu, v.w & 0x7FFFFFFFu };
    bool s[4];
    unsigned cnt = 0;
#pragma unroll
    for (int c = 0; c < 4; ++c) { s[c] = (k[c] <= G); cnt += (unsigned)s[c]; }
    unsigned incl = cnt;
    for (int off = 1; off < 64; off <<= 1) {
      unsigned u = __shfl_up(incl, off, 64);
      if (lane >= off) incl += u;
    }
    const unsigned wtot = __shfl(incl, 63, 64);
    unsigned pos = base + incl - cnt;
#pragma unroll
    for (int c = 0; c < 4; ++c) {
      if (s[c]) {
        if (pos < (unsigned)KCAP) {
          ka[pos] = k[c];
          atomicAdd(&h2[(k[c] & 255u) * NB_S + pos / (unsigned)CH_S], 1u);
        }
        ++pos;
      }
    }
    base += wtot;
  }
  __syncthreads();
  unsigned* Hb = H0 + (size_t)b * 256 * NB_S;
  for (int e = tid; e < 256 * NB_S; e += TPB) {
    unsigned c = h2[e];
    if (c) atomicAdd(&Hb[e], c);
  }
}

// per-sample scan of H[b][256][NB_S] counts -> global output bases
__global__ __launch_bounds__(TPB) void k_hscan(unsigned* __restrict__ H) {
  __shared__ unsigned wsum[4];
  const int b = blockIdx.x, tid = threadIdx.x;
  const int lane = tid & 63, wv = tid >> 6;
  unsigned* Hb = H + (size_t)b * 256 * NB_S;
  unsigned row[NB_S];
  unsigned run = 0;
#pragma unroll
  for (int k = 0; k < NB_S; ++k) {
    unsigned t = Hb[tid * NB_S + k];
    row[k] = run; run += t;
  }
  unsigned incl = run;
  for (int off = 1; off < 64; off <<= 1) {
    unsigned t = __shfl_up(incl, off, 64);
    if (lane >= off) incl += t;
  }
  if (lane == 63) wsum[wv] = incl;
  __syncthreads();
  unsigned wpre = 0;
  for (int w = 0; w < wv; ++w) wpre += wsum[w];
  const unsigned excl = incl - run + wpre;
#pragma unroll
  for (int k = 0; k < NB_S; ++k) Hb[tid * NB_S + k] = row[k] + excl;
}

// scan Hf[b][64][NB_S] (49 rows used) -> pairbuf bases; one wave per sample
__global__ __launch_bounds__(64) void k_hscanF(unsigned* __restrict__ Hf) {
  const int b = blockIdx.x, tid = threadIdx.x;
  unsigned* Hb = Hf + (size_t)b * 64 * NB_S;
  unsigned row[NB_S];
  unsigned run = 0;
  if (tid < NFB) {
#pragma unroll
    for (int k = 0; k < NB_S; ++k) {
      unsigned t = Hb[tid * NB_S + k];
      row[k] = run; run += t;
    }
  }
  unsigned incl = run;
  for (int off = 1; off < 64; off <<= 1) {
    unsigned t = __shfl_up(incl, off, 64);
    if (tid >= off) incl += t;
  }
  const unsigned excl = incl - run;
  if (tid < NFB) {
#pragma unroll
    for (int k = 0; k < NB_S; ++k) Hb[tid * NB_S + k] = row[k] + excl;
  }
}

// One stable 8-bit LSD radix pass, TPS=1024 threads, tile=4096 records.
// MODE 0: 4B key array -> records + next hist. MODE 1: records -> records + hist (+Hf).
template<int MODE>
__global__ __launch_bounds__(TPS) void k_sort8(const unsigned* __restrict__ keyIn,
                                               const uint2* __restrict__ inR,
                                               uint2* __restrict__ outR,
                                               const unsigned* __restrict__ Hcur,
                                               unsigned* __restrict__ Hnext,
                                               unsigned* __restrict__ Hf,
                                               const unsigned* __restrict__ ws,
                                               int shift) {
  __shared__ unsigned wh[16][256];
  __shared__ unsigned gout[256];
  __shared__ unsigned gbase[256];
  __shared__ unsigned wsum[4];
  __shared__ uint2    stg[TILE];
  __shared__ unsigned h2[256 * NB_S];
  __shared__ unsigned h2f[(MODE == 1) ? NFB * NB_S : 1];
  const int bid = blockIdx.x;
  const int b = bid & 63, blk = bid >> 6, tid = threadIdx.x;
  const int lane = tid & 63, wv = tid >> 6;
  const unsigned long long ltm = (1ull << lane) - 1ull;
  const unsigned kp = min(ws[WS_KP + b], (unsigned)KCAP);
  const unsigned s0 = (unsigned)blk * CH_S;
  const unsigned s1 = min(s0 + (unsigned)CH_S, kp);
  const unsigned* ki = keyIn + (size_t)b * KCAP;
  const uint2* in = inR + (size_t)b * KCAP;
  uint2* out = outR + (size_t)b * KCAP;
  const bool doF = (MODE == 1) && (Hf != nullptr);

  for (int d = tid; d < 256; d += TPS) gbase[d] = Hcur[((size_t)b * 256 + d) * NB_S + blk];
  for (int e = tid; e < 256 * NB_S; e += TPS) h2[e] = 0u;
  if (MODE == 1) { if (doF) for (int e = tid; e < NFB * NB_S; e += TPS) h2f[e] = 0u; }
  __syncthreads();

  for (unsigned t0 = s0; t0 < s1; t0 += (unsigned)TILE) {
    { uint4* w4 = (uint4*)&wh[0][0];
      w4[tid] = make_uint4(0u, 0u, 0u, 0u); }
    __syncthreads();

    unsigned key[4], cpp[4], wloc[4], dig[4];
    bool val[4];
    const unsigned wbase = t0 + (unsigned)wv * 256u;
#pragma unroll
    for (int c = 0; c < 4; ++c) {
      const unsigned i = wbase + (unsigned)c * 64u + (unsigned)lane;
      val[c] = (i < s1);
      if (MODE == 0) { cpp[c] = i; key[c] = val[c] ? ki[i] : 0u; }
      else { uint2 r = val[c] ? in[i] : make_uint2(0u, 0u); cpp[c] = r.x; key[c] = r.y; }
      dig[c] = (key[c] >> shift) & 255u;
      unsigned long long peers = __ballot(val[c]);
#pragma unroll
      for (int bit = 0; bit < 8; ++bit) {
        unsigned long long bb = __ballot(val[c] && ((dig[c] >> bit) & 1u));
        peers &= ((dig[c] >> bit) & 1u) ? bb : ~bb;
      }
      const unsigned before = (unsigned)__popcll(peers & ltm);
      int ldr = __ffsll((unsigned long long)peers) - 1;
      if (ldr < 0) ldr = 0;
      unsigned old = 0;
      if (val[c] && lane == ldr) old = atomicAdd(&wh[wv][dig[c]], (unsigned)__popcll(peers));
      old = __shfl(old, ldr, 64);
      wloc[c] = old + before;
    }
    __syncthreads();

    unsigned incl = 0, tot = 0;
    if (tid < 256) {
      const unsigned d = (unsigned)tid;
#pragma unroll
      for (int w = 0; w < 16; ++w) tot += wh[w][d];
      incl = tot;
      for (int off = 1; off < 64; off <<= 1) {
        unsigned t = __shfl_up(incl, off, 64);
        if (lane >= off) incl += t;
      }
      if (lane == 63) wsum[wv] = incl;
    }
    __syncthreads();
    if (tid < 256) {
      const unsigned d = (unsigned)tid;
      unsigned wpre = 0;
      for (int w = 0; w < wv; ++w) wpre += wsum[w];
      const unsigned tstart = incl - tot + wpre;
      const unsigned g = gbase[d];
      gout[d] = g - tstart;
      gbase[d] = g + tot;
      unsigned run = tstart;
#pragma unroll
      for (int w = 0; w < 16; ++w) { const unsigned t = wh[w][d]; wh[w][d] = run; run += t; }
    }
    __syncthreads();

#pragma unroll
    for (int c = 0; c < 4; ++c) {
      if (val[c]) {
        uint2 r; r.x = cpp[c]; r.y = key[c];
        stg[wh[wv][dig[c]] + wloc[c]] = r;
      }
    }
    __syncthreads();
    const unsigned nt = min((unsigned)TILE, s1 - t0);
    for (unsigned j = tid; j < nt; j += TPS) {
      const uint2 r = stg[j];
      const unsigned d = (r.y >> shift) & 255u;
      const unsigned pos = gout[d] + j;
      out[pos] = r;
      const unsigned nd = (r.y >> (shift + 8)) & 255u;
      atomicAdd(&h2[nd * NB_S + pos / (unsigned)CH_S], 1u);
      if (doF) atomicAdd(&h2f[(r.x >> 12) * NB_S + pos / (unsigned)CH_S], 1u);
    }
    __syncthreads();
  }

  {
    unsigned* Hb = Hnext + (size_t)b * 256 * NB_S;
    for (int e = tid; e < 256 * NB_S; e += TPS) {
      unsigned c = h2[e];
      if (c) atomicAdd(&Hb[e], c);
    }
    if (doF) {
      unsigned* Hfb = Hf + (size_t)b * 64 * NB_S;
      for (int e = tid; e < NFB * NB_S; e += TPS) {
        unsigned c = h2f[e];
        if (c) atomicAdd(&Hfb[e], c);
      }
    }
  }
}

// Final pass (lightweight): 7-bit key-digit stable ranking -> exact rank,
// then bin (cpp, rank) by cpp>>12 via LDS atomics (order-free) and write COALESCED.
__global__ __launch_bounds__(TPS) void k_final(const uint2* __restrict__ inR,
                                               uint2* __restrict__ pairOut,
                                               const unsigned* __restrict__ Hcur,
                                               const unsigned* __restrict__ Hf,
                                               const unsigned* __restrict__ ws) {
  __shared__ unsigned wh[16][128];     // key-digit counts -> absolute rank bases
  __shared__ unsigned gbase[128];
  __shared__ unsigned whF[16][64];     // fill-bin counts -> tile staging offsets
  __shared__ unsigned goutF[64];
  __shared__ unsigned gbaseF[64];
  __shared__ uint2    stg[TILE];
  const int bid = blockIdx.x;
  const int b = bid & 63, blk = bid >> 6, tid = threadIdx.x;
  const int lane = tid & 63, wv = tid >> 6;
  const unsigned long long ltm = (1ull << lane) - 1ull;
  const unsigned kp = min(ws[WS_KP + b], (unsigned)KCAP);
  const unsigned s0 = (unsigned)blk * CH_S;
  const unsigned s1 = min(s0 + (unsigned)CH_S, kp);
  const uint2* in = inR + (size_t)b * KCAP;
  uint2* po = pairOut + (size_t)b * KCAP;

  for (int d = tid; d < 128; d += TPS) gbase[d] = Hcur[((size_t)b * 256 + d) * NB_S + blk];
  for (int d = tid; d < 64; d += TPS)
    gbaseF[d] = (d < NFB) ? Hf[((size_t)b * 64 + d) * NB_S + blk] : 0u;
  __syncthreads();

  for (unsigned t0 = s0; t0 < s1; t0 += (unsigned)TILE) {
    { uint4* p = (uint4*)&wh[0][0];
      if (tid < 512) p[tid] = make_uint4(0u, 0u, 0u, 0u);
      uint4* q = (uint4*)&whF[0][0];
      if (tid >= 512 && tid < 768) q[tid - 512] = make_uint4(0u, 0u, 0u, 0u); }
    __syncthreads();

    // Phase A: key-digit (7-bit) stable ranking
    unsigned key[4], cpp[4], wloc[4], dig[4];
    bool val[4];
    const unsigned wbase = t0 + (unsigned)wv * 256u;
#pragma unroll
    for (int c = 0; c < 4; ++c) {
      const unsigned i = wbase + (unsigned)c * 64u + (unsigned)lane;
      val[c] = (i < s1);
      uint2 r = val[c] ? in[i] : make_uint2(0u, 0u);
      cpp[c] = r.x; key[c] = r.y;
      dig[c] = (key[c] >> 24) & 127u;
      unsigned long long peers = __ballot(val[c]);
#pragma unroll
      for (int bit = 0; bit < 7; ++bit) {
        unsigned long long bb = __ballot(val[c] && ((dig[c] >> bit) & 1u));
        peers &= ((dig[c] >> bit) & 1u) ? bb : ~bb;
      }
      const unsigned before = (unsigned)__popcll(peers & ltm);
      int ldr = __ffsll((unsigned long long)peers) - 1;
      if (ldr < 0) ldr = 0;
      unsigned old = 0;
      if (val[c] && lane == ldr) old = atomicAdd(&wh[wv][dig[c]], (unsigned)__popcll(peers));
      old = __shfl(old, ldr, 64);
      wloc[c] = old + before;
    }
    __syncthreads();

    // Phase B: wh -> absolute rank bases per wave; advance gbase
    if (tid < 128) {
      const unsigned d = (unsigned)tid;
      unsigned run = gbase[d];
#pragma unroll
      for (int w = 0; w < 16; ++w) { const unsigned t = wh[w][d]; wh[w][d] = run; run += t; }
      gbase[d] = run;
    }
    __syncthreads();

    // rank + fill-bin offset via LDS atomic (order within bin irrelevant)
    unsigned rnk[4], dbF[4], wlocF[4];
#pragma unroll
    for (int c = 0; c < 4; ++c) {
      dbF[c] = cpp[c] >> 12;
      if (val[c]) {
        rnk[c] = wh[wv][dig[c]] + wloc[c];
        wlocF[c] = atomicAdd(&whF[wv][dbF[c]], 1u);
      }
    }
    __syncthreads();

    // Phase B2: tile-local staging offsets for fill bins (single wave)
    if (tid < 64) {
      const unsigned d = (unsigned)tid;
      unsigned tot = 0;
      if (d < NFB) {
#pragma unroll
        for (int w = 0; w < 16; ++w) tot += whF[w][d];
      }
      unsigned incl = tot;
      for (int off = 1; off < 64; off <<= 1) {
        unsigned t = __shfl_up(incl, off, 64);
        if (lane >= off) incl += t;
      }
      const unsigned tstart = incl - tot;
      goutF[d] = gbaseF[d] - tstart;
      gbaseF[d] += tot;
      unsigned run = tstart;
#pragma unroll
      for (int w = 0; w < 16; ++w) { const unsigned t = whF[w][d]; whF[w][d] = run; run += t; }
    }
    __syncthreads();

    // Phase C2: stage (cpp, rank) by fill bin
#pragma unroll
    for (int c = 0; c < 4; ++c) {
      if (val[c]) {
        uint2 r; r.x = cpp[c]; r.y = rnk[c];
        stg[whF[wv][dbF[c]] + wlocF[c]] = r;
      }
    }
    __syncthreads();

    // Phase D2: coalesced pair write-out
    const unsigned nt = min((unsigned)TILE, s1 - t0);
    for (unsigned j = tid; j < nt; j += TPS) {
      const uint2 r = stg[j];
      po[goutF[r.x >> 12] + j] = r;
    }
    __syncthreads();
  }
}

// Unpack: per (sample, fill-bin) block — threefry on dense lanes, LDS scatter,
// write fm linearly.
__global__ __launch_bounds__(TPB) void k_unpack(const uint2* __restrict__ pairs,
                                                unsigned* __restrict__ fm,
                                                const unsigned* __restrict__ ws) {
  __shared__ unsigned vals[4096];
  const int bid = blockIdx.x;
  const int b = bid & 63, d = bid >> 6, tid = threadIdx.x;
  const unsigned kp = min(ws[WS_KP + b], (unsigned)KCAP);
  const unsigned start = (unsigned)d * 4096u;
  if (start >= kp) return;
  const unsigned cnt = min(4096u, kp - start);
  const unsigned S0 = ws[WS_S0 + b], S01 = ws[WS_S01 + b];
  const float* mnf = (const float*)(ws + WS_MN);
  const float* mxf = (const float*)(ws + WS_MX);
  const float l0 = mnf[b * CCH], l1 = mnf[b * CCH + 1], l2 = mnf[b * CCH + 2];
  const float h0 = mxf[b * CCH], h1 = mxf[b * CCH + 1], h2v = mxf[b * CCH + 2];
  const uint2* pb = pairs + (size_t)b * KCAP + start;
  for (unsigned j = tid; j < cnt; j += TPB) {
    const uint2 r = pb[j];
    unsigned res = 0xFFFFFFFFu;
    if (r.y < (unsigned)KSEL) {
      const unsigned p = (unsigned)b * (unsigned)KSEL + r.y;
      unsigned o0, o1;
      threefry2x32(0u, 42u, 0u, p, o0, o1);
      const unsigned bits = o0 ^ o1;
      const float u = __uint_as_float((bits >> 9) | 0x3f800000u) - 1.0f;
      const unsigned ch = (unsigned)(r.x >= S0) + (unsigned)(r.x >= S01);
      const float lo = (ch == 0) ? l0 : ((ch == 1) ? l1 : l2);
      const float hi = (ch == 0) ? h0 : ((ch == 1) ? h1 : h2v);
      res = __float_as_uint(lo + u * (hi - lo));
    }
    vals[r.x & 4095u] = res;
  }
  __syncthreads();
  unsigned* f = fm + (size_t)b * KCAP + start;
  for (unsigned j = tid; j < cnt; j += TPB) f[j] = vals[j];
}

// Fused copy+fill: regenerates compaction positions (same traversal as cscatter);
// reads fill VALUES from fm sequentially; nt streaming for x/g/out.
__global__ __launch_bounds__(TPB) void k_fill(const u32x4* __restrict__ x4,
                                              const u32x4* __restrict__ g4all,
                                              const unsigned* __restrict__ fillmap,
                                              const unsigned* __restrict__ ws,
                                              u32x4* __restrict__ out4) {
  const int bid = blockIdx.x;
  const int b = bid & 63, blk = bid >> 6, tid = threadIdx.x;
  const int lane = tid & 63, wv = tid >> 6;
  const unsigned G = ws[WS_GS + b];
  const unsigned kp = min(ws[WS_KP + b], (unsigned)KCAP);
  unsigned base = ws[WS_COFF + b * 256 + blk * 4 + wv];
  const size_t t4 = (size_t)b * (NPS / 4) + (size_t)blk * (CH_C / 4) + (size_t)wv * (WCH / 4);
  const unsigned* fm = fillmap + (size_t)b * KCAP;
  for (int it = 0; it < WCH / 256; ++it) {
    const size_t a = t4 + it * 64 + lane;
    const u32x4 gv = __builtin_nontemporal_load(&g4all[a]);
    u32x4 xv = __builtin_nontemporal_load(&x4[a]);
    unsigned k[4] = { gv.x & 0x7FFFFFFFu, gv.y & 0x7FFFFFFFu, gv.z & 0x7FFFFFFFu, gv.w & 0x7FFFFFFFu };
    bool s[4];
    unsigned cnt = 0;
#pragma unroll
    for (int c = 0; c < 4; ++c) { s[c] = (k[c] <= G); cnt += (unsigned)s[c]; }
    unsigned incl = cnt;
    for (int off = 1; off < 64; off <<= 1) {
      unsigned u = __shfl_up(incl, off, 64);
      if (lane >= off) incl += u;
    }
    const unsigned wtot = __shfl(incl, 63, 64);
    unsigned pos = base + incl - cnt;
#pragma unroll
    for (int c = 0; c < 4; ++c) {
      if (s[c]) {
        if (pos < kp) {
          const unsigned r = fm[pos];
          if (r != 0xFFFFFFFFu) xv[c] = r;
        }
        ++pos;
      }
    }
    __builtin_nontemporal_store(xv, &out4[a]);
    base += wtot;
  }
}

extern "C" void kernel_launch(void* const* d_in, const int* in_sizes, int n_in,
                              void* d_out, int out_size, void* d_ws, size_t ws_size,
                              hipStream_t stream) {
  const float* x = (const float*)d_in[0];
  const unsigned* gb = (const unsigned*)d_in[1];   // grad bits
  float* out = (float*)d_out;
  unsigned* ws = (unsigned*)d_ws;
  if (ws_size < WS_NEEDED_BYTES) return;

  unsigned* R1 = ws + WS_FIX_END;                  // keys / records / pairs
  unsigned* R2 = ws + WS_FIX_END + RECW;           // append scratch / records / fm
  unsigned* H0 = ws + WS_H0;
  unsigned* H1 = ws + WS_H1;
  unsigned* H2 = ws + WS_H2;
  unsigned* H3 = ws + WS_H3;
  unsigned* HF = ws + WS_HF;

  dim3 blk(TPB);
  dim3 sblk(TPS);

  // 0. min/max partials ; zero accumulated region (CNT2..FIX_END)
  k_mnmx<<<dim3(BN * CCH * SUB), blk, 0, stream>>>((const float4*)x, ws);
  k_mnfin<<<dim3(1), blk, 0, stream>>>(ws);
  {
    const int nz = (int)(WS_FIX_END - WS_CNT2);
    k_zero<<<dim3((nz + TPB - 1) / TPB), blk, 0, stream>>>(ws + WS_CNT2, nz);
  }

  // 1. threshold refinement: thrA ; fused thrB+rangecount ; cc2 on boundary matches
  k_thrA<<<dim3(NB_T, BN), blk, 0, stream>>>(gb, ws + WS_THA);
  k_find<<<dim3(BN), blk, 0, stream>>>(ws + WS_THA, ws, 0);
  k_thrBC<<<dim3(NB_C * BN), blk, 0, stream>>>(gb, ws + WS_THB, R2, ws);
  k_find<<<dim3(BN), blk, 0, stream>>>(ws + WS_THB, ws, 1);
  k_cc2<<<dim3(BN), blk, 0, stream>>>(R2, ws);
  k_cscan<<<dim3(BN), blk, 0, stream>>>(ws);

  // 2. index-ordered compaction (4B keys) + fused pass-1 histogram
  k_cscatter<<<dim3(NB_C * BN), blk, 0, stream>>>(gb, ws, R1, H0);

  // 3. stable LSD radix sort on keys (8/8/8), pass 3 also builds fill-bin hist HF
  k_hscan<<<dim3(BN), blk, 0, stream>>>(H0);
  k_sort8<0><<<dim3(NB_S * BN), sblk, 0, stream>>>(R1, (const uint2*)nullptr, (uint2*)R2, H0, H1, nullptr, ws, 0);
  k_hscan<<<dim3(BN), blk, 0, stream>>>(H1);
  k_sort8<1><<<dim3(NB_S * BN), sblk, 0, stream>>>(nullptr, (const uint2*)R2, (uint2*)R1, H1, H2, nullptr, ws, 8);
  k_hscan<<<dim3(BN), blk, 0, stream>>>(H2);
  k_sort8<1><<<dim3(NB_S * BN), sblk, 0, stream>>>(nullptr, (const uint2*)R1, (uint2*)R2, H2, H3, HF, ws, 16);
  k_hscan<<<dim3(BN), blk, 0, stream>>>(H3);
  k_hscanF<<<dim3(BN), dim3(64), 0, stream>>>(HF);

  // 4. final: rank + binned coalesced (cpp,rank) pairs ; unpack (threefry) -> fm
  k_final<<<dim3(NB_S * BN), sblk, 0, stream>>>((const uint2*)R2, (uint2*)R1, H3, HF, ws);
  k_unpack<<<dim3(NFB * BN), blk, 0, stream>>>((const uint2*)R1, R2, ws);

  // 5. fused copy + fill (pure streaming)
  k_fill<<<dim3(NB_C * BN), blk, 0, stream>>>((const u32x4*)x, (const u32x4*)gb, R2, ws, (u32x4*)out);
}

// Round 12
// 707.022 us; speedup vs baseline: 6.0000x; 6.0000x over previous
//
#include <hip/hip_runtime.h>
#include <stdint.h>

#define TPB 256
#define TPS 1024          // threads per sort block

// Problem constants
constexpr int BN   = 64;          // batch
constexpr int CCH  = 3;           // channels
constexpr int HWS  = 262144;      // H*W
constexpr int LOG_HW = 18;
constexpr int NPS  = 786432;      // C*H*W per sample
constexpr int KSEL = 196608;      // K_UPPER
constexpr int KCAP = 200704;      // KSEL + slack for boundary duplicates
constexpr int NB_T = 32;          // blocks/sample for thrA scan
constexpr int CH_T = NPS / NB_T;  // 24576
constexpr int NB_C = 64;          // blocks/sample for compaction/fill scans
constexpr int CH_C = NPS / NB_C;  // 12288
constexpr int WCH  = CH_C / 4;    // 3072 elements per wave subrange
constexpr int NB_S = 8;           // blocks/sample for sort passes
constexpr int CH_S = KCAP / NB_S; // 25088
constexpr int TILE = 4096;        // records per sort tile (TPS * 4)
constexpr int NBINS = 2048;       // threshold-refinement bins
constexpr int SUB  = 8;           // sub-blocks per (b,c) in mnmx
constexpr int NFB  = 49;          // fill bins: KCAP / 4096
constexpr int ASLOT = 1024;       // append slot per wave-range (expected ~134 entries)
constexpr int ACAP = 256 * ASLOT; // per-sample append region

// native vector type for nontemporal builtins (HIP uint4 is a class type)
typedef unsigned u32x4 __attribute__((ext_vector_type(4)));

// ws layout (u32 offsets)
constexpr int WS_MN   = 0;        // f32[192]
constexpr int WS_MX   = 192;      // f32[192]
constexpr int WS_V1   = 384;      // u32[64]
constexpr int WS_B1   = 448;      // u32[64]
constexpr int WS_V2   = 512;      // u32[64]
constexpr int WS_GS   = 576;      // u32[64] inclusive key threshold G*
constexpr int WS_KP   = 640;      // u32[64] compacted count per sample
constexpr int WS_S0   = 704;      // u32[64] selected in ch0
constexpr int WS_S01  = 768;      // u32[64] selected in ch0+ch1
constexpr int WS_CNT  = 832;                      // u32[64][256] cntLess per wave-range
constexpr int WS_COFF = WS_CNT + BN * 256;        // 17216
constexpr int WS_MNP  = WS_COFF + BN * 256;       // 33600 ; f32[1536]
constexpr int WS_MXP  = WS_MNP + BN * CCH * SUB;  // 35136 ; f32[1536]
constexpr int WS_CNT2 = WS_MXP + BN * CCH * SUB;  // 36672 ; u32[64][256] boundary counts
constexpr int WS_RC   = WS_CNT2 + BN * 256;       // 53056 ; u32[64][256] per-range append counts
// ---- zeroed-each-launch region starts here ----
constexpr int WS_CHC  = WS_RC + BN * 256;         // 69440 ; u32[64][4] channel-selected counts
constexpr int WS_THA  = WS_CHC + BN * 4;          // 69696
constexpr int WS_THB  = WS_THA + BN * NBINS;      // 200768
constexpr int WS_H0   = WS_THB + BN * NBINS;      // 331840 ; u32[64][256][NB_S]
constexpr int WS_H1   = WS_H0 + BN * 256 * NB_S;
constexpr int WS_H2   = WS_H1 + BN * 256 * NB_S;
constexpr int WS_H3   = WS_H2 + BN * 256 * NB_S;
constexpr int WS_HF   = WS_H3 + BN * 256 * NB_S;  // u32[64][64][NB_S] fill-bin hist
constexpr size_t WS_FIX_END = (size_t)WS_HF + (size_t)BN * 64 * NB_S;   // 888896 words
constexpr size_t RECW = (size_t)BN * KCAP * 2;   // words per uint2 record buffer
constexpr size_t WS_NEEDED_BYTES = (WS_FIX_END + 2 * RECW) * 4;   // ~209.1 MB (proven-safe)
static_assert((size_t)BN * ACAP <= RECW, "append scratch must fit in R2");

// ---------------- threefry2x32 (JAX-exact, partitionable stream) ----------------
__device__ __forceinline__ unsigned rotl32(unsigned x, int r) { return (x << r) | (x >> (32 - r)); }

__device__ __forceinline__ void tf4(unsigned& x0, unsigned& x1, int a, int b, int c, int d) {
  x0 += x1; x1 = rotl32(x1, a); x1 ^= x0;
  x0 += x1; x1 = rotl32(x1, b); x1 ^= x0;
  x0 += x1; x1 = rotl32(x1, c); x1 ^= x0;
  x0 += x1; x1 = rotl32(x1, d); x1 ^= x0;
}

__device__ __forceinline__ void threefry2x32(unsigned k0, unsigned k1, unsigned c0, unsigned c1,
                                             unsigned& o0, unsigned& o1) {
  const unsigned ks2 = k0 ^ k1 ^ 0x1BD11BDAu;
  unsigned x0 = c0 + k0, x1 = c1 + k1;
  tf4(x0, x1, 13, 15, 26, 6);  x0 += k1;  x1 += ks2 + 1u;
  tf4(x0, x1, 17, 29, 16, 24); x0 += ks2; x1 += k0 + 2u;
  tf4(x0, x1, 13, 15, 26, 6);  x0 += k0;  x1 += k1 + 3u;
  tf4(x0, x1, 17, 29, 16, 24); x0 += k1;  x1 += ks2 + 4u;
  tf4(x0, x1, 13, 15, 26, 6);  x0 += ks2; x1 += k0 + 5u;
  o0 = x0; o1 = x1;
}

// ---------------- kernels ----------------
__global__ __launch_bounds__(TPB) void k_zero(unsigned* __restrict__ p, int n) {
  int i = blockIdx.x * TPB + threadIdx.x;
  if (i < n) p[i] = 0u;
}

// per-(b,c) min/max partials (excluding channel's last element) — read-only
__global__ __launch_bounds__(TPB) void k_mnmx(const float4* __restrict__ x,
                                              unsigned* __restrict__ ws) {
  __shared__ float smn[TPB], smx[TPB];
  const int g = blockIdx.x;            // bc*SUB + sub
  const int bc = g / SUB, sub = g - bc * SUB;
  const int Q4 = HWS / 4 / SUB;
  const size_t base4 = (size_t)bc * (HWS / 4) + (size_t)sub * Q4;
  const bool last = (sub == SUB - 1);
  const int tid = threadIdx.x;
  float lo = 3.4e38f, hi = -3.4e38f;
  for (int i = tid; i < Q4; i += TPB) {
    float4 v = x[base4 + i];
    if (last && i == Q4 - 1) {         // exclude final element of the channel
      lo = fminf(lo, fminf(fminf(v.x, v.y), v.z));
      hi = fmaxf(hi, fmaxf(fmaxf(v.x, v.y), v.z));
    } else {
      lo = fminf(lo, fminf(fminf(v.x, v.y), fminf(v.z, v.w)));
      hi = fmaxf(hi, fmaxf(fmaxf(v.x, v.y), fmaxf(v.z, v.w)));
    }
  }
  smn[tid] = lo; smx[tid] = hi; __syncthreads();
  for (int s = TPB / 2; s > 0; s >>= 1) {
    if (tid < s) { smn[tid] = fminf(smn[tid], smn[tid + s]); smx[tid] = fmaxf(smx[tid], smx[tid + s]); }
    __syncthreads();
  }
  if (tid == 0) {
    ((float*)(ws + WS_MNP))[g] = smn[0];
    ((float*)(ws + WS_MXP))[g] = smx[0];
  }
}

__global__ __launch_bounds__(TPB) void k_mnfin(unsigned* __restrict__ ws) {
  const int t = threadIdx.x;
  if (t < BN * CCH) {
    const float* mnp = (const float*)(ws + WS_MNP);
    const float* mxp = (const float*)(ws + WS_MXP);
    float lo = 3.4e38f, hi = -3.4e38f;
    for (int s = 0; s < SUB; ++s) {
      lo = fminf(lo, mnp[t * SUB + s]);
      hi = fmaxf(hi, mxp[t * SUB + s]);
    }
    ((float*)(ws + WS_MN))[t] = lo;
    ((float*)(ws + WS_MX))[t] = hi;
  }
}

__global__ __launch_bounds__(TPB) void k_thrA(const unsigned* __restrict__ gb, unsigned* __restrict__ hist) {
  __shared__ unsigned h[NBINS];
  const int b = blockIdx.y, blk = blockIdx.x, tid = threadIdx.x;
  for (int v = tid; v < NBINS; v += TPB) h[v] = 0u;
  __syncthreads();
  const uint4* g4 = (const uint4*)(gb + (size_t)b * NPS + (size_t)blk * CH_T);
  for (int i = tid; i < CH_T / 4; i += TPB) {
    uint4 v = g4[i];
    atomicAdd(&h[(v.x & 0x7FFFFFFFu) >> 21], 1u);
    atomicAdd(&h[(v.y & 0x7FFFFFFFu) >> 21], 1u);
    atomicAdd(&h[(v.z & 0x7FFFFFFFu) >> 21], 1u);
    atomicAdd(&h[(v.w & 0x7FFFFFFFu) >> 21], 1u);
  }
  __syncthreads();
  unsigned* gh = hist + (size_t)b * NBINS;
  for (int v = tid; v < NBINS; v += TPB) if (h[v]) atomicAdd(&gh[v], h[v]);
}

// Fused second refinement + range-count pass (replaces thrB AND ccount):
// per-wave-range count(top < V1), per-channel cntLess totals,
// mid-11 histogram of top==V1 matches, SEGMENTED per-range append (no atomics).
__global__ __launch_bounds__(TPB) void k_thrBC(const unsigned* __restrict__ gb,
                                               unsigned* __restrict__ hist,
                                               unsigned* __restrict__ app,
                                               unsigned* __restrict__ ws) {
  __shared__ unsigned h[NBINS];
  __shared__ unsigned chs[3];
  const int bid = blockIdx.x;
  const int b = bid & 63, blk = bid >> 6, tid = threadIdx.x;
  const int lane = tid & 63, wv = tid >> 6;
  const unsigned long long ltm = (1ull << lane) - 1ull;
  for (int v = tid; v < NBINS; v += TPB) h[v] = 0u;
  if (tid < 3) chs[tid] = 0u;
  __syncthreads();
  const unsigned V1 = ws[WS_V1 + b];
  const unsigned rangeId = (unsigned)(blk * 4 + wv);
  const uint4* g4 = (const uint4*)(gb + (size_t)b * NPS + (size_t)blk * CH_C) + wv * (WCH / 4);
  const unsigned e0 = (unsigned)blk * CH_C + (unsigned)wv * WCH;
  unsigned* ap = app + (size_t)b * ACAP + (size_t)rangeId * ASLOT;
  unsigned abase = 0;                       // wave-uniform running append offset
  unsigned cntLess = 0, cc0 = 0, cc1 = 0, cc2 = 0;
  for (int it = 0; it < WCH / 256; ++it) {
    const uint4 v = g4[it * 64 + lane];
    const unsigned e = e0 + (unsigned)it * 256u + (unsigned)lane * 4u;
    const unsigned k[4] = { v.x & 0x7FFFFFFFu, v.y & 0x7FFFFFFFu, v.z & 0x7FFFFFFFu, v.w & 0x7FFFFFFFu };
#pragma unroll
    for (int c = 0; c < 4; ++c) {
      const unsigned top = k[c] >> 21;
      const bool isEq = (top == V1);
      if (top < V1) {
        ++cntLess;
        const unsigned ch = (e + (unsigned)c) >> LOG_HW;
        if (ch == 0) ++cc0; else if (ch == 1) ++cc1; else ++cc2;
      } else if (isEq) {
        atomicAdd(&h[(k[c] >> 10) & 2047u], 1u);
      }
      unsigned long long m = __ballot(isEq);
      if (isEq) {
        const unsigned ai = abase + (unsigned)__popcll(m & ltm);
        if (ai < (unsigned)ASLOT) {
          const unsigned ch = (e + (unsigned)c) >> LOG_HW;
          ap[ai] = (ch << 11) | ((k[c] >> 10) & 2047u);
        }
      }
      abase += (unsigned)__popcll(m);
    }
  }
  if (lane == 0) ws[WS_RC + b * 256 + rangeId] = min(abase, (unsigned)ASLOT);
  for (int off = 32; off >= 1; off >>= 1) cntLess += __shfl_down(cntLess, off, 64);
  if (lane == 0) ws[WS_CNT + b * 256 + rangeId] = cntLess;
  if (cc0) atomicAdd(&chs[0], cc0);
  if (cc1) atomicAdd(&chs[1], cc1);
  if (cc2) atomicAdd(&chs[2], cc2);
  __syncthreads();
  if (tid < 3 && chs[tid]) atomicAdd(&ws[WS_CHC + b * 4 + tid], chs[tid]);
  unsigned* gh = hist + (size_t)b * NBINS;
  for (int v = tid; v < NBINS; v += TPB) if (h[v]) atomicAdd(&gh[v], h[v]);
}

// mode 0: top bits -> V1, B1 ; mode 1: mid 11 bits -> V2, G*, Kp
__global__ __launch_bounds__(TPB) void k_find(const unsigned* __restrict__ hist,
                                              unsigned* __restrict__ ws, int mode) {
  __shared__ unsigned part[TPB];
  const int b = blockIdx.x, tid = threadIdx.x;
  const unsigned* h = hist + (size_t)b * NBINS;
  const int per = NBINS / TPB;
  const unsigned Kt = (mode == 0) ? (unsigned)KSEL : (unsigned)KSEL - ws[WS_B1 + b];
  unsigned vals[8];
  unsigned s = 0;
  for (int j = 0; j < per; ++j) { vals[j] = h[tid * per + j]; s += vals[j]; }
  part[tid] = s; __syncthreads();
  for (int off = 1; off < TPB; off <<= 1) {
    unsigned t = (tid >= off) ? part[tid - off] : 0u;
    __syncthreads(); part[tid] += t; __syncthreads();
  }
  unsigned run = part[tid] - s;
  for (int j = 0; j < per; ++j) {
    const unsigned lo = run, c = vals[j];
    run += c;
    if (lo < Kt && Kt <= run) {
      const unsigned v = (unsigned)(tid * per + j);
      if (mode == 0) {
        ws[WS_V1 + b] = v; ws[WS_B1 + b] = lo;
      } else {
        ws[WS_V2 + b] = v;
        const unsigned T22 = (ws[WS_V1 + b] << 11) | v;
        ws[WS_GS + b] = (T22 << 10) | 1023u;        // inclusive 31-bit threshold
        unsigned kp = ws[WS_B1 + b] + lo + c;       // countLess + countEq
        if (kp > (unsigned)KCAP) kp = (unsigned)KCAP;
        ws[WS_KP + b] = kp;
      }
    }
  }
}

// count boundary-bin matches with mid <= V2 per wave-range + per channel.
// thread-per-range serial count (~134 entries each, L2-resident).
__global__ __launch_bounds__(TPB) void k_cc2(const unsigned* __restrict__ app,
                                             unsigned* __restrict__ ws) {
  __shared__ unsigned lch[3];
  const int b = blockIdx.x, tid = threadIdx.x;
  if (tid < 3) lch[tid] = 0u;
  __syncthreads();
  const unsigned V2 = ws[WS_V2 + b];
  const unsigned cnt = ws[WS_RC + b * 256 + tid];
  const unsigned* ap = app + (size_t)b * ACAP + (size_t)tid * ASLOT;
  unsigned n2 = 0, c0 = 0, c1 = 0, c2 = 0;
  for (unsigned i = 0; i < cnt; ++i) {
    const unsigned e = ap[i];
    if ((e & 2047u) <= V2) {
      ++n2;
      const unsigned ch = (e >> 11) & 3u;
      if (ch == 0) ++c0; else if (ch == 1) ++c1; else ++c2;
    }
  }
  ws[WS_CNT2 + b * 256 + tid] = n2;
  if (c0) atomicAdd(&lch[0], c0);
  if (c1) atomicAdd(&lch[1], c1);
  if (c2) atomicAdd(&lch[2], c2);
  __syncthreads();
  if (tid < 3 && lch[tid]) atomicAdd(&ws[WS_CHC + b * 4 + tid], lch[tid]);
}

// scan 256 per-wave-range totals (cntLess + cnt2) -> COFF ; channel boundaries
__global__ __launch_bounds__(TPB) void k_cscan(unsigned* __restrict__ ws) {
  __shared__ unsigned wsum[4];
  const int b = blockIdx.x, tid = threadIdx.x;
  const int lane = tid & 63, wv = tid >> 6;
  const unsigned cnt = ws[WS_CNT + b * 256 + tid] + ws[WS_CNT2 + b * 256 + tid];
  unsigned incl = cnt;
  for (int off = 1; off < 64; off <<= 1) {
    unsigned t = __shfl_up(incl, off, 64);
    if (lane >= off) incl += t;
  }
  if (lane == 63) wsum[wv] = incl;
  __syncthreads();
  unsigned wpre = 0;
  for (int w = 0; w < wv; ++w) wpre += wsum[w];
  ws[WS_COFF + b * 256 + tid] = incl - cnt + wpre;
  if (tid == 0) {
    const unsigned s0 = ws[WS_CHC + b * 4 + 0];
    ws[WS_S0 + b] = s0;
    ws[WS_S01 + b] = s0 + ws[WS_CHC + b * 4 + 1];
  }
}

// Index-ordered compaction (wave-independent) -> 4B keys, fused pass-1 hist H0.
__global__ __launch_bounds__(TPB) void k_cscatter(const unsigned* __restrict__ gb,
                                                  const unsigned* __restrict__ ws,
                                                  unsigned* __restrict__ keyArr,
                                                  unsigned* __restrict__ H0) {
  __shared__ unsigned h2[256 * NB_S];   // 8 KB
  const int bid = blockIdx.x;
  const int b = bid & 63, blk = bid >> 6, tid = threadIdx.x;
  const int lane = tid & 63, wv = tid >> 6;
  for (int e = tid; e < 256 * NB_S; e += TPB) h2[e] = 0u;
  __syncthreads();
  const unsigned G = ws[WS_GS + b];
  unsigned base = ws[WS_COFF + b * 256 + blk * 4 + wv];
  const uint4* g4 = (const uint4*)(gb + (size_t)b * NPS + (size_t)blk * CH_C) + wv * (WCH / 4);
  unsigned* ka = keyArr + (size_t)b * KCAP;
  for (int it = 0; it < WCH / 256; ++it) {
    const uint4 v = g4[it * 64 + lane];
    unsigned k[4] = { v.x & 0x7FFFFFFFu, v.y & 0x7FFFFFFFu, v.z & 0x7FFFFFFFu, v.w & 0x7FFFFFFFu };
    bool s[4];
    unsigned cnt = 0;
#pragma unroll
    for (int c = 0; c < 4; ++c) { s[c] = (k[c] <= G); cnt += (unsigned)s[c]; }
    unsigned incl = cnt;
    for (int off = 1; off < 64; off <<= 1) {
      unsigned u = __shfl_up(incl, off, 64);
      if (lane >= off) incl += u;
    }
    const unsigned wtot = __shfl(incl, 63, 64);
    unsigned pos = base + incl - cnt;
#pragma unroll
    for (int c = 0; c < 4; ++c) {
      if (s[c]) {
        if (pos < (unsigned)KCAP) {
          ka[pos] = k[c];
          atomicAdd(&h2[(k[c] & 255u) * NB_S + pos / (unsigned)CH_S], 1u);
        }
        ++pos;
      }
    }
    base += wtot;
  }
  __syncthreads();
  unsigned* Hb = H0 + (size_t)b * 256 * NB_S;
  for (int e = tid; e < 256 * NB_S; e += TPB) {
    unsigned c = h2[e];
    if (c) atomicAdd(&Hb[e], c);
  }
}

// per-sample scan of H[b][256][NB_S] counts -> global output bases
__global__ __launch_bounds__(TPB) void k_hscan(unsigned* __restrict__ H) {
  __shared__ unsigned wsum[4];
  const int b = blockIdx.x, tid = threadIdx.x;
  const int lane = tid & 63, wv = tid >> 6;
  unsigned* Hb = H + (size_t)b * 256 * NB_S;
  unsigned row[NB_S];
  unsigned run = 0;
#pragma unroll
  for (int k = 0; k < NB_S; ++k) {
    unsigned t = Hb[tid * NB_S + k];
    row[k] = run; run += t;
  }
  unsigned incl = run;
  for (int off = 1; off < 64; off <<= 1) {
    unsigned t = __shfl_up(incl, off, 64);
    if (lane >= off) incl += t;
  }
  if (lane == 63) wsum[wv] = incl;
  __syncthreads();
  unsigned wpre = 0;
  for (int w = 0; w < wv; ++w) wpre += wsum[w];
  const unsigned excl = incl - run + wpre;
#pragma unroll
  for (int k = 0; k < NB_S; ++k) Hb[tid * NB_S + k] = row[k] + excl;
}

// scan Hf[b][64][NB_S] (49 rows used) -> pairbuf bases; one wave per sample
__global__ __launch_bounds__(64) void k_hscanF(unsigned* __restrict__ Hf) {
  const int b = blockIdx.x, tid = threadIdx.x;
  unsigned* Hb = Hf + (size_t)b * 64 * NB_S;
  unsigned row[NB_S];
  unsigned run = 0;
  if (tid < NFB) {
#pragma unroll
    for (int k = 0; k < NB_S; ++k) {
      unsigned t = Hb[tid * NB_S + k];
      row[k] = run; run += t;
    }
  }
  unsigned incl = run;
  for (int off = 1; off < 64; off <<= 1) {
    unsigned t = __shfl_up(incl, off, 64);
    if (tid >= off) incl += t;
  }
  const unsigned excl = incl - run;
  if (tid < NFB) {
#pragma unroll
    for (int k = 0; k < NB_S; ++k) Hb[tid * NB_S + k] = row[k] + excl;
  }
}

// One stable 8-bit LSD radix pass, TPS=1024 threads, tile=4096 records.
// MODE 0: 4B key array -> records + next hist. MODE 1: records -> records + hist (+Hf).
template<int MODE>
__global__ __launch_bounds__(TPS) void k_sort8(const unsigned* __restrict__ keyIn,
                                               const uint2* __restrict__ inR,
                                               uint2* __restrict__ outR,
                                               const unsigned* __restrict__ Hcur,
                                               unsigned* __restrict__ Hnext,
                                               unsigned* __restrict__ Hf,
                                               const unsigned* __restrict__ ws,
                                               int shift) {
  __shared__ unsigned wh[16][256];
  __shared__ unsigned gout[256];
  __shared__ unsigned gbase[256];
  __shared__ unsigned wsum[4];
  __shared__ uint2    stg[TILE];
  __shared__ unsigned h2[256 * NB_S];
  __shared__ unsigned h2f[(MODE == 1) ? NFB * NB_S : 1];
  const int bid = blockIdx.x;
  const int b = bid & 63, blk = bid >> 6, tid = threadIdx.x;
  const int lane = tid & 63, wv = tid >> 6;
  const unsigned long long ltm = (1ull << lane) - 1ull;
  const unsigned kp = min(ws[WS_KP + b], (unsigned)KCAP);
  const unsigned s0 = (unsigned)blk * CH_S;
  const unsigned s1 = min(s0 + (unsigned)CH_S, kp);
  const unsigned* ki = keyIn + (size_t)b * KCAP;
  const uint2* in = inR + (size_t)b * KCAP;
  uint2* out = outR + (size_t)b * KCAP;
  const bool doF = (MODE == 1) && (Hf != nullptr);

  for (int d = tid; d < 256; d += TPS) gbase[d] = Hcur[((size_t)b * 256 + d) * NB_S + blk];
  for (int e = tid; e < 256 * NB_S; e += TPS) h2[e] = 0u;
  if (MODE == 1) { if (doF) for (int e = tid; e < NFB * NB_S; e += TPS) h2f[e] = 0u; }
  __syncthreads();

  for (unsigned t0 = s0; t0 < s1; t0 += (unsigned)TILE) {
    { uint4* w4 = (uint4*)&wh[0][0];
      w4[tid] = make_uint4(0u, 0u, 0u, 0u); }
    __syncthreads();

    unsigned key[4], cpp[4], wloc[4], dig[4];
    bool val[4];
    const unsigned wbase = t0 + (unsigned)wv * 256u;
#pragma unroll
    for (int c = 0; c < 4; ++c) {
      const unsigned i = wbase + (unsigned)c * 64u + (unsigned)lane;
      val[c] = (i < s1);
      if (MODE == 0) { cpp[c] = i; key[c] = val[c] ? ki[i] : 0u; }
      else { uint2 r = val[c] ? in[i] : make_uint2(0u, 0u); cpp[c] = r.x; key[c] = r.y; }
      dig[c] = (key[c] >> shift) & 255u;
      unsigned long long peers = __ballot(val[c]);
#pragma unroll
      for (int bit = 0; bit < 8; ++bit) {
        unsigned long long bb = __ballot(val[c] && ((dig[c] >> bit) & 1u));
        peers &= ((dig[c] >> bit) & 1u) ? bb : ~bb;
      }
      const unsigned before = (unsigned)__popcll(peers & ltm);
      int ldr = __ffsll((unsigned long long)peers) - 1;
      if (ldr < 0) ldr = 0;
      unsigned old = 0;
      if (val[c] && lane == ldr) old = atomicAdd(&wh[wv][dig[c]], (unsigned)__popcll(peers));
      old = __shfl(old, ldr, 64);
      wloc[c] = old + before;
    }
    __syncthreads();

    unsigned incl = 0, tot = 0;
    if (tid < 256) {
      const unsigned d = (unsigned)tid;
#pragma unroll
      for (int w = 0; w < 16; ++w) tot += wh[w][d];
      incl = tot;
      for (int off = 1; off < 64; off <<= 1) {
        unsigned t = __shfl_up(incl, off, 64);
        if (lane >= off) incl += t;
      }
      if (lane == 63) wsum[wv] = incl;
    }
    __syncthreads();
    if (tid < 256) {
      const unsigned d = (unsigned)tid;
      unsigned wpre = 0;
      for (int w = 0; w < wv; ++w) wpre += wsum[w];
      const unsigned tstart = incl - tot + wpre;
      const unsigned g = gbase[d];
      gout[d] = g - tstart;
      gbase[d] = g + tot;
      unsigned run = tstart;
#pragma unroll
      for (int w = 0; w < 16; ++w) { const unsigned t = wh[w][d]; wh[w][d] = run; run += t; }
    }
    __syncthreads();

#pragma unroll
    for (int c = 0; c < 4; ++c) {
      if (val[c]) {
        uint2 r; r.x = cpp[c]; r.y = key[c];
        stg[wh[wv][dig[c]] + wloc[c]] = r;
      }
    }
    __syncthreads();
    const unsigned nt = min((unsigned)TILE, s1 - t0);
    for (unsigned j = tid; j < nt; j += TPS) {
      const uint2 r = stg[j];
      const unsigned d = (r.y >> shift) & 255u;
      const unsigned pos = gout[d] + j;
      out[pos] = r;
      const unsigned nd = (r.y >> (shift + 8)) & 255u;
      atomicAdd(&h2[nd * NB_S + pos / (unsigned)CH_S], 1u);
      if (doF) atomicAdd(&h2f[(r.x >> 12) * NB_S + pos / (unsigned)CH_S], 1u);
    }
    __syncthreads();
  }

  {
    unsigned* Hb = Hnext + (size_t)b * 256 * NB_S;
    for (int e = tid; e < 256 * NB_S; e += TPS) {
      unsigned c = h2[e];
      if (c) atomicAdd(&Hb[e], c);
    }
    if (doF) {
      unsigned* Hfb = Hf + (size_t)b * 64 * NB_S;
      for (int e = tid; e < NFB * NB_S; e += TPS) {
        unsigned c = h2f[e];
        if (c) atomicAdd(&Hfb[e], c);
      }
    }
  }
}

// Final pass (lightweight): 7-bit key-digit stable ranking -> exact rank,
// then bin (cpp, rank) by cpp>>12 via LDS atomics (order-free) and write COALESCED.
__global__ __launch_bounds__(TPS) void k_final(const uint2* __restrict__ inR,
                                               uint2* __restrict__ pairOut,
                                               const unsigned* __restrict__ Hcur,
                                               const unsigned* __restrict__ Hf,
                                               const unsigned* __restrict__ ws) {
  __shared__ unsigned wh[16][128];     // key-digit counts -> absolute rank bases
  __shared__ unsigned gbase[128];
  __shared__ unsigned whF[16][64];     // fill-bin counts -> tile staging offsets
  __shared__ unsigned goutF[64];
  __shared__ unsigned gbaseF[64];
  __shared__ uint2    stg[TILE];
  const int bid = blockIdx.x;
  const int b = bid & 63, blk = bid >> 6, tid = threadIdx.x;
  const int lane = tid & 63, wv = tid >> 6;
  const unsigned long long ltm = (1ull << lane) - 1ull;
  const unsigned kp = min(ws[WS_KP + b], (unsigned)KCAP);
  const unsigned s0 = (unsigned)blk * CH_S;
  const unsigned s1 = min(s0 + (unsigned)CH_S, kp);
  const uint2* in = inR + (size_t)b * KCAP;
  uint2* po = pairOut + (size_t)b * KCAP;

  for (int d = tid; d < 128; d += TPS) gbase[d] = Hcur[((size_t)b * 256 + d) * NB_S + blk];
  for (int d = tid; d < 64; d += TPS)
    gbaseF[d] = (d < NFB) ? Hf[((size_t)b * 64 + d) * NB_S + blk] : 0u;
  __syncthreads();

  for (unsigned t0 = s0; t0 < s1; t0 += (unsigned)TILE) {
    { uint4* p = (uint4*)&wh[0][0];
      if (tid < 512) p[tid] = make_uint4(0u, 0u, 0u, 0u);
      uint4* q = (uint4*)&whF[0][0];
      if (tid >= 512 && tid < 768) q[tid - 512] = make_uint4(0u, 0u, 0u, 0u); }
    __syncthreads();

    // Phase A: key-digit (7-bit) stable ranking
    unsigned key[4], cpp[4], wloc[4], dig[4];
    bool val[4];
    const unsigned wbase = t0 + (unsigned)wv * 256u;
#pragma unroll
    for (int c = 0; c < 4; ++c) {
      const unsigned i = wbase + (unsigned)c * 64u + (unsigned)lane;
      val[c] = (i < s1);
      uint2 r = val[c] ? in[i] : make_uint2(0u, 0u);
      cpp[c] = r.x; key[c] = r.y;
      dig[c] = (key[c] >> 24) & 127u;
      unsigned long long peers = __ballot(val[c]);
#pragma unroll
      for (int bit = 0; bit < 7; ++bit) {
        unsigned long long bb = __ballot(val[c] && ((dig[c] >> bit) & 1u));
        peers &= ((dig[c] >> bit) & 1u) ? bb : ~bb;
      }
      const unsigned before = (unsigned)__popcll(peers & ltm);
      int ldr = __ffsll((unsigned long long)peers) - 1;
      if (ldr < 0) ldr = 0;
      unsigned old = 0;
      if (val[c] && lane == ldr) old = atomicAdd(&wh[wv][dig[c]], (unsigned)__popcll(peers));
      old = __shfl(old, ldr, 64);
      wloc[c] = old + before;
    }
    __syncthreads();

    // Phase B: wh -> absolute rank bases per wave; advance gbase
    if (tid < 128) {
      const unsigned d = (unsigned)tid;
      unsigned run = gbase[d];
#pragma unroll
      for (int w = 0; w < 16; ++w) { const unsigned t = wh[w][d]; wh[w][d] = run; run += t; }
      gbase[d] = run;
    }
    __syncthreads();

    // rank + fill-bin offset via LDS atomic (order within bin irrelevant)
    unsigned rnk[4], dbF[4], wlocF[4];
#pragma unroll
    for (int c = 0; c < 4; ++c) {
      dbF[c] = cpp[c] >> 12;
      if (val[c]) {
        rnk[c] = wh[wv][dig[c]] + wloc[c];
        wlocF[c] = atomicAdd(&whF[wv][dbF[c]], 1u);
      }
    }
    __syncthreads();

    // Phase B2: tile-local staging offsets for fill bins (single wave)
    if (tid < 64) {
      const unsigned d = (unsigned)tid;
      unsigned tot = 0;
      if (d < NFB) {
#pragma unroll
        for (int w = 0; w < 16; ++w) tot += whF[w][d];
      }
      unsigned incl = tot;
      for (int off = 1; off < 64; off <<= 1) {
        unsigned t = __shfl_up(incl, off, 64);
        if (lane >= off) incl += t;
      }
      const unsigned tstart = incl - tot;
      goutF[d] = gbaseF[d] - tstart;
      gbaseF[d] += tot;
      unsigned run = tstart;
#pragma unroll
      for (int w = 0; w < 16; ++w) { const unsigned t = whF[w][d]; whF[w][d] = run; run += t; }
    }
    __syncthreads();

    // Phase C2: stage (cpp, rank) by fill bin
#pragma unroll
    for (int c = 0; c < 4; ++c) {
      if (val[c]) {
        uint2 r; r.x = cpp[c]; r.y = rnk[c];
        stg[whF[wv][dbF[c]] + wlocF[c]] = r;
      }
    }
    __syncthreads();

    // Phase D2: coalesced pair write-out
    const unsigned nt = min((unsigned)TILE, s1 - t0);
    for (unsigned j = tid; j < nt; j += TPS) {
      const uint2 r = stg[j];
      po[goutF[r.x >> 12] + j] = r;
    }
    __syncthreads();
  }
}

// Unpack: per (sample, fill-bin) block — threefry on dense lanes, LDS scatter,
// write fm linearly.
__global__ __launch_bounds__(TPB) void k_unpack(const uint2* __restrict__ pairs,
                                                unsigned* __restrict__ fm,
                                                const unsigned* __restrict__ ws) {
  __shared__ unsigned vals[4096];
  const int bid = blockIdx.x;
  const int b = bid & 63, d = bid >> 6, tid = threadIdx.x;
  const unsigned kp = min(ws[WS_KP + b], (unsigned)KCAP);
  const unsigned start = (unsigned)d * 4096u;
  if (start >= kp) return;
  const unsigned cnt = min(4096u, kp - start);
  const unsigned S0 = ws[WS_S0 + b], S01 = ws[WS_S01 + b];
  const float* mnf = (const float*)(ws + WS_MN);
  const float* mxf = (const float*)(ws + WS_MX);
  const float l0 = mnf[b * CCH], l1 = mnf[b * CCH + 1], l2 = mnf[b * CCH + 2];
  const float h0 = mxf[b * CCH], h1 = mxf[b * CCH + 1], h2v = mxf[b * CCH + 2];
  const uint2* pb = pairs + (size_t)b * KCAP + start;
  for (unsigned j = tid; j < cnt; j += TPB) {
    const uint2 r = pb[j];
    unsigned res = 0xFFFFFFFFu;
    if (r.y < (unsigned)KSEL) {
      const unsigned p = (unsigned)b * (unsigned)KSEL + r.y;
      unsigned o0, o1;
      threefry2x32(0u, 42u, 0u, p, o0, o1);
      const unsigned bits = o0 ^ o1;
      const float u = __uint_as_float((bits >> 9) | 0x3f800000u) - 1.0f;
      const unsigned ch = (unsigned)(r.x >= S0) + (unsigned)(r.x >= S01);
      const float lo = (ch == 0) ? l0 : ((ch == 1) ? l1 : l2);
      const float hi = (ch == 0) ? h0 : ((ch == 1) ? h1 : h2v);
      res = __float_as_uint(lo + u * (hi - lo));
    }
    vals[r.x & 4095u] = res;
  }
  __syncthreads();
  unsigned* f = fm + (size_t)b * KCAP + start;
  for (unsigned j = tid; j < cnt; j += TPB) f[j] = vals[j];
}

// Fused copy+fill: regenerates compaction positions (same traversal as cscatter);
// reads fill VALUES from fm sequentially; nt streaming for x/g/out.
__global__ __launch_bounds__(TPB) void k_fill(const u32x4* __restrict__ x4,
                                              const u32x4* __restrict__ g4all,
                                              const unsigned* __restrict__ fillmap,
                                              const unsigned* __restrict__ ws,
                                              u32x4* __restrict__ out4) {
  const int bid = blockIdx.x;
  const int b = bid & 63, blk = bid >> 6, tid = threadIdx.x;
  const int lane = tid & 63, wv = tid >> 6;
  const unsigned G = ws[WS_GS + b];
  const unsigned kp = min(ws[WS_KP + b], (unsigned)KCAP);
  unsigned base = ws[WS_COFF + b * 256 + blk * 4 + wv];
  const size_t t4 = (size_t)b * (NPS / 4) + (size_t)blk * (CH_C / 4) + (size_t)wv * (WCH / 4);
  const unsigned* fm = fillmap + (size_t)b * KCAP;
  for (int it = 0; it < WCH / 256; ++it) {
    const size_t a = t4 + it * 64 + lane;
    const u32x4 gv = __builtin_nontemporal_load(&g4all[a]);
    u32x4 xv = __builtin_nontemporal_load(&x4[a]);
    unsigned k[4] = { gv.x & 0x7FFFFFFFu, gv.y & 0x7FFFFFFFu, gv.z & 0x7FFFFFFFu, gv.w & 0x7FFFFFFFu };
    bool s[4];
    unsigned cnt = 0;
#pragma unroll
    for (int c = 0; c < 4; ++c) { s[c] = (k[c] <= G); cnt += (unsigned)s[c]; }
    unsigned incl = cnt;
    for (int off = 1; off < 64; off <<= 1) {
      unsigned u = __shfl_up(incl, off, 64);
      if (lane >= off) incl += u;
    }
    const unsigned wtot = __shfl(incl, 63, 64);
    unsigned pos = base + incl - cnt;
#pragma unroll
    for (int c = 0; c < 4; ++c) {
      if (s[c]) {
        if (pos < kp) {
          const unsigned r = fm[pos];
          if (r != 0xFFFFFFFFu) xv[c] = r;
        }
        ++pos;
      }
    }
    __builtin_nontemporal_store(xv, &out4[a]);
    base += wtot;
  }
}

extern "C" void kernel_launch(void* const* d_in, const int* in_sizes, int n_in,
                              void* d_out, int out_size, void* d_ws, size_t ws_size,
                              hipStream_t stream) {
  const float* x = (const float*)d_in[0];
  const unsigned* gb = (const unsigned*)d_in[1];   // grad bits
  float* out = (float*)d_out;
  unsigned* ws = (unsigned*)d_ws;
  if (ws_size < WS_NEEDED_BYTES) return;

  unsigned* R1 = ws + WS_FIX_END;                  // keys / records / pairs
  unsigned* R2 = ws + WS_FIX_END + RECW;           // append scratch / records / fm
  unsigned* H0 = ws + WS_H0;
  unsigned* H1 = ws + WS_H1;
  unsigned* H2 = ws + WS_H2;
  unsigned* H3 = ws + WS_H3;
  unsigned* HF = ws + WS_HF;

  dim3 blk(TPB);
  dim3 sblk(TPS);

  // 0. min/max partials ; zero atomically-accumulated region (CHC..FIX_END)
  k_mnmx<<<dim3(BN * CCH * SUB), blk, 0, stream>>>((const float4*)x, ws);
  k_mnfin<<<dim3(1), blk, 0, stream>>>(ws);
  {
    const int nz = (int)(WS_FIX_END - WS_CHC);
    k_zero<<<dim3((nz + TPB - 1) / TPB), blk, 0, stream>>>(ws + WS_CHC, nz);
  }

  // 1. threshold refinement: thrA ; fused thrB+rangecount (segmented append) ; cc2
  k_thrA<<<dim3(NB_T, BN), blk, 0, stream>>>(gb, ws + WS_THA);
  k_find<<<dim3(BN), blk, 0, stream>>>(ws + WS_THA, ws, 0);
  k_thrBC<<<dim3(NB_C * BN), blk, 0, stream>>>(gb, ws + WS_THB, R2, ws);
  k_find<<<dim3(BN), blk, 0, stream>>>(ws + WS_THB, ws, 1);
  k_cc2<<<dim3(BN), blk, 0, stream>>>(R2, ws);
  k_cscan<<<dim3(BN), blk, 0, stream>>>(ws);

  // 2. index-ordered compaction (4B keys) + fused pass-1 histogram
  k_cscatter<<<dim3(NB_C * BN), blk, 0, stream>>>(gb, ws, R1, H0);

  // 3. stable LSD radix sort on keys (8/8/8), pass 3 also builds fill-bin hist HF
  k_hscan<<<dim3(BN), blk, 0, stream>>>(H0);
  k_sort8<0><<<dim3(NB_S * BN), sblk, 0, stream>>>(R1, (const uint2*)nullptr, (uint2*)R2, H0, H1, nullptr, ws, 0);
  k_hscan<<<dim3(BN), blk, 0, stream>>>(H1);
  k_sort8<1><<<dim3(NB_S * BN), sblk, 0, stream>>>(nullptr, (const uint2*)R2, (uint2*)R1, H1, H2, nullptr, ws, 8);
  k_hscan<<<dim3(BN), blk, 0, stream>>>(H2);
  k_sort8<1><<<dim3(NB_S * BN), sblk, 0, stream>>>(nullptr, (const uint2*)R1, (uint2*)R2, H2, H3, HF, ws, 16);
  k_hscan<<<dim3(BN), blk, 0, stream>>>(H3);
  k_hscanF<<<dim3(BN), dim3(64), 0, stream>>>(HF);

  // 4. final: rank + binned coalesced (cpp,rank) pairs ; unpack (threefry) -> fm
  k_final<<<dim3(NB_S * BN), sblk, 0, stream>>>((const uint2*)R2, (uint2*)R1, H3, HF, ws);
  k_unpack<<<dim3(NFB * BN), blk, 0, stream>>>((const uint2*)R1, R2, ws);

  // 5. fused copy + fill (pure streaming)
  k_fill<<<dim3(NB_C * BN), blk, 0, stream>>>((const u32x4*)x, (const u32x4*)gb, R2, ws, (u32x4*)out);
}

// Round 13
// 705.172 us; speedup vs baseline: 6.0157x; 1.0026x over previous
//
#include <hip/hip_runtime.h>
#include <stdint.h>

#define TPB 256
#define TPS 1024          // threads per sort block

// Problem constants
constexpr int BN   = 64;          // batch
constexpr int CCH  = 3;           // channels
constexpr int HWS  = 262144;      // H*W
constexpr int LOG_HW = 18;
constexpr int NPS  = 786432;      // C*H*W per sample
constexpr int KSEL = 196608;      // K_UPPER
constexpr int KCAP = 200704;      // KSEL + slack for boundary duplicates
constexpr int NB_T = 32;          // blocks/sample for thrA scan
constexpr int CH_T = NPS / NB_T;  // 24576
constexpr int NB_C = 64;          // blocks/sample for compaction/fill scans
constexpr int CH_C = NPS / NB_C;  // 12288
constexpr int NRNG = 768;         // ranges per sample (1024 elements each)
constexpr int NB_S = 8;           // blocks/sample for sort passes
constexpr int CH_S = KCAP / NB_S; // 25088
constexpr int TILE = 4096;        // records per sort tile (TPS * 4)
constexpr int NBINS = 2048;       // threshold-refinement bins
constexpr int SUB  = 8;           // sub-blocks per (b,c) in mnmx
constexpr int NFB  = 49;          // fill bins: KCAP / 4096
constexpr int ASLOT = 256;        // append slot per range (expected ~48 entries)
constexpr int ACAP = NRNG * ASLOT; // per-sample append region (196608 words)
constexpr int BMPW = NPS / 32;    // bitmap words per sample (24576)

// native vector type for nontemporal builtins (HIP uint4 is a class type)
typedef unsigned u32x4 __attribute__((ext_vector_type(4)));

// ws layout (u32 offsets)
constexpr int WS_MN   = 0;        // f32[192]
constexpr int WS_MX   = 192;      // f32[192]
constexpr int WS_V1   = 384;      // u32[64]
constexpr int WS_B1   = 448;      // u32[64]
constexpr int WS_V2   = 512;      // u32[64]
constexpr int WS_GS   = 576;      // u32[64] inclusive key threshold G*
constexpr int WS_KP   = 640;      // u32[64] compacted count per sample
constexpr int WS_S0   = 704;      // u32[64] selected in ch0
constexpr int WS_S01  = 768;      // u32[64] selected in ch0+ch1
constexpr int WS_CNT  = 832;                      // u32[64][768] cntLess per range
constexpr int WS_COFF = WS_CNT + BN * NRNG;       // 49984
constexpr int WS_MNP  = WS_COFF + BN * NRNG;      // 99136 ; f32[1536]
constexpr int WS_MXP  = WS_MNP + BN * CCH * SUB;  // 100672 ; f32[1536]
constexpr int WS_CNT2 = WS_MXP + BN * CCH * SUB;  // 102208 ; u32[64][768] boundary counts
constexpr int WS_RC   = WS_CNT2 + BN * NRNG;      // 151360 ; u32[64][768] append counts
// ---- zeroed-each-launch region starts here ----
constexpr int WS_CHC  = WS_RC + BN * NRNG;        // 200512 ; u32[64][4] channel counts
constexpr int WS_THA  = WS_CHC + BN * 4;          // 200768
constexpr int WS_THB  = WS_THA + BN * NBINS;      // 331840
constexpr int WS_H0   = WS_THB + BN * NBINS;      // 462912 ; u32[64][256][NB_S]
constexpr int WS_H1   = WS_H0 + BN * 256 * NB_S;
constexpr int WS_H2   = WS_H1 + BN * 256 * NB_S;
constexpr int WS_H3   = WS_H2 + BN * 256 * NB_S;
constexpr int WS_HF   = WS_H3 + BN * 256 * NB_S;  // u32[64][64][NB_S] fill-bin hist
constexpr size_t WS_FIX_END = (size_t)WS_HF + (size_t)BN * 64 * NB_S;   // 1019968 words
constexpr size_t RECW = (size_t)BN * KCAP * 2;   // words per uint2 record buffer
constexpr size_t WS_NEEDED_BYTES = (WS_FIX_END + 2 * RECW) * 4;            // 209.6 MB (proven-safe)
constexpr size_t WS_BMP_OFF = WS_FIX_END + 2 * RECW;
constexpr size_t WS_NEEDED_BMP = (WS_BMP_OFF + (size_t)BN * BMPW) * 4;     // 215.9 MB (opportunistic)
static_assert((size_t)BN * ACAP <= RECW, "append scratch must fit in R2");

// ---------------- threefry2x32 (JAX-exact, partitionable stream) ----------------
__device__ __forceinline__ unsigned rotl32(unsigned x, int r) { return (x << r) | (x >> (32 - r)); }

__device__ __forceinline__ void tf4(unsigned& x0, unsigned& x1, int a, int b, int c, int d) {
  x0 += x1; x1 = rotl32(x1, a); x1 ^= x0;
  x0 += x1; x1 = rotl32(x1, b); x1 ^= x0;
  x0 += x1; x1 = rotl32(x1, c); x1 ^= x0;
  x0 += x1; x1 = rotl32(x1, d); x1 ^= x0;
}

__device__ __forceinline__ void threefry2x32(unsigned k0, unsigned k1, unsigned c0, unsigned c1,
                                             unsigned& o0, unsigned& o1) {
  const unsigned ks2 = k0 ^ k1 ^ 0x1BD11BDAu;
  unsigned x0 = c0 + k0, x1 = c1 + k1;
  tf4(x0, x1, 13, 15, 26, 6);  x0 += k1;  x1 += ks2 + 1u;
  tf4(x0, x1, 17, 29, 16, 24); x0 += ks2; x1 += k0 + 2u;
  tf4(x0, x1, 13, 15, 26, 6);  x0 += k0;  x1 += k1 + 3u;
  tf4(x0, x1, 17, 29, 16, 24); x0 += k1;  x1 += ks2 + 4u;
  tf4(x0, x1, 13, 15, 26, 6);  x0 += ks2; x1 += k0 + 5u;
  o0 = x0; o1 = x1;
}

// ---------------- kernels ----------------
__global__ __launch_bounds__(TPB) void k_zero(unsigned* __restrict__ p, int n) {
  int i = blockIdx.x * TPB + threadIdx.x;
  if (i < n) p[i] = 0u;
}

// per-(b,c) min/max partials (excluding channel's last element) — read-only
__global__ __launch_bounds__(TPB) void k_mnmx(const float4* __restrict__ x,
                                              unsigned* __restrict__ ws) {
  __shared__ float smn[TPB], smx[TPB];
  const int g = blockIdx.x;            // bc*SUB + sub
  const int bc = g / SUB, sub = g - bc * SUB;
  const int Q4 = HWS / 4 / SUB;
  const size_t base4 = (size_t)bc * (HWS / 4) + (size_t)sub * Q4;
  const bool last = (sub == SUB - 1);
  const int tid = threadIdx.x;
  float lo = 3.4e38f, hi = -3.4e38f;
  for (int i = tid; i < Q4; i += TPB) {
    float4 v = x[base4 + i];
    if (last && i == Q4 - 1) {         // exclude final element of the channel
      lo = fminf(lo, fminf(fminf(v.x, v.y), v.z));
      hi = fmaxf(hi, fmaxf(fmaxf(v.x, v.y), v.z));
    } else {
      lo = fminf(lo, fminf(fminf(v.x, v.y), fminf(v.z, v.w)));
      hi = fmaxf(hi, fmaxf(fmaxf(v.x, v.y), fmaxf(v.z, v.w)));
    }
  }
  smn[tid] = lo; smx[tid] = hi; __syncthreads();
  for (int s = TPB / 2; s > 0; s >>= 1) {
    if (tid < s) { smn[tid] = fminf(smn[tid], smn[tid + s]); smx[tid] = fmaxf(smx[tid], smx[tid + s]); }
    __syncthreads();
  }
  if (tid == 0) {
    ((float*)(ws + WS_MNP))[g] = smn[0];
    ((float*)(ws + WS_MXP))[g] = smx[0];
  }
}

__global__ __launch_bounds__(TPB) void k_mnfin(unsigned* __restrict__ ws) {
  const int t = threadIdx.x;
  if (t < BN * CCH) {
    const float* mnp = (const float*)(ws + WS_MNP);
    const float* mxp = (const float*)(ws + WS_MXP);
    float lo = 3.4e38f, hi = -3.4e38f;
    for (int s = 0; s < SUB; ++s) {
      lo = fminf(lo, mnp[t * SUB + s]);
      hi = fmaxf(hi, mxp[t * SUB + s]);
    }
    ((float*)(ws + WS_MN))[t] = lo;
    ((float*)(ws + WS_MX))[t] = hi;
  }
}

__global__ __launch_bounds__(TPB) void k_thrA(const unsigned* __restrict__ gb, unsigned* __restrict__ hist) {
  __shared__ unsigned h[NBINS];
  const int b = blockIdx.y, blk = blockIdx.x, tid = threadIdx.x;
  for (int v = tid; v < NBINS; v += TPB) h[v] = 0u;
  __syncthreads();
  const uint4* g4 = (const uint4*)(gb + (size_t)b * NPS + (size_t)blk * CH_T);
  for (int i = tid; i < CH_T / 4; i += TPB) {
    uint4 v = g4[i];
    atomicAdd(&h[(v.x & 0x7FFFFFFFu) >> 21], 1u);
    atomicAdd(&h[(v.y & 0x7FFFFFFFu) >> 21], 1u);
    atomicAdd(&h[(v.z & 0x7FFFFFFFu) >> 21], 1u);
    atomicAdd(&h[(v.w & 0x7FFFFFFFu) >> 21], 1u);
  }
  __syncthreads();
  unsigned* gh = hist + (size_t)b * NBINS;
  for (int v = tid; v < NBINS; v += TPB) if (h[v]) atomicAdd(&gh[v], h[v]);
}

// Fused second refinement + range-count pass:
// per-range (1024 elems) count(top < V1), per-channel totals, mid-11 hist of
// boundary matches, SEGMENTED per-range append (no global atomics).
__global__ __launch_bounds__(TPB) void k_thrBC(const unsigned* __restrict__ gb,
                                               unsigned* __restrict__ hist,
                                               unsigned* __restrict__ app,
                                               unsigned* __restrict__ ws) {
  __shared__ unsigned h[NBINS];
  __shared__ unsigned chs[3];
  const int bid = blockIdx.x;
  const int b = bid & 63, blk = bid >> 6, tid = threadIdx.x;
  const int lane = tid & 63, wv = tid >> 6;
  const unsigned long long ltm = (1ull << lane) - 1ull;
  for (int v = tid; v < NBINS; v += TPB) h[v] = 0u;
  if (tid < 3) chs[tid] = 0u;
  __syncthreads();
  const unsigned V1 = ws[WS_V1 + b];
  const uint4* g4 = (const uint4*)(gb + (size_t)b * NPS + (size_t)blk * CH_C) + wv * 768;
  unsigned cc0 = 0, cc1 = 0, cc2 = 0;
  for (int r = 0; r < 3; ++r) {
    const unsigned rangeId = (unsigned)((blk * 4 + wv) * 3 + r);
    unsigned* ap = app + (size_t)b * ACAP + (size_t)rangeId * ASLOT;
    unsigned abase = 0, cntLess = 0;
#pragma unroll
    for (int it = 0; it < 4; ++it) {
      const uint4 v = g4[r * 256 + it * 64 + lane];
      const unsigned e = (unsigned)blk * CH_C + (unsigned)wv * 3072u + (unsigned)r * 1024u
                       + (unsigned)it * 256u + (unsigned)lane * 4u;
      const unsigned k[4] = { v.x & 0x7FFFFFFFu, v.y & 0x7FFFFFFFu, v.z & 0x7FFFFFFFu, v.w & 0x7FFFFFFFu };
#pragma unroll
      for (int c = 0; c < 4; ++c) {
        const unsigned top = k[c] >> 21;
        const bool isEq = (top == V1);
        if (top < V1) {
          ++cntLess;
          const unsigned ch = (e + (unsigned)c) >> LOG_HW;
          if (ch == 0) ++cc0; else if (ch == 1) ++cc1; else ++cc2;
        } else if (isEq) {
          atomicAdd(&h[(k[c] >> 10) & 2047u], 1u);
        }
        unsigned long long m = __ballot(isEq);
        if (isEq) {
          const unsigned ai = abase + (unsigned)__popcll(m & ltm);
          if (ai < (unsigned)ASLOT) {
            const unsigned ch = (e + (unsigned)c) >> LOG_HW;
            ap[ai] = (ch << 11) | ((k[c] >> 10) & 2047u);
          }
        }
        abase += (unsigned)__popcll(m);
      }
    }
    unsigned cl = cntLess;
    for (int off = 32; off >= 1; off >>= 1) cl += __shfl_down(cl, off, 64);
    if (lane == 0) {
      ws[WS_CNT + b * NRNG + rangeId] = cl;
      ws[WS_RC + b * NRNG + rangeId] = min(abase, (unsigned)ASLOT);
    }
  }
  if (cc0) atomicAdd(&chs[0], cc0);
  if (cc1) atomicAdd(&chs[1], cc1);
  if (cc2) atomicAdd(&chs[2], cc2);
  __syncthreads();
  if (tid < 3 && chs[tid]) atomicAdd(&ws[WS_CHC + b * 4 + tid], chs[tid]);
  unsigned* gh = hist + (size_t)b * NBINS;
  for (int v = tid; v < NBINS; v += TPB) if (h[v]) atomicAdd(&gh[v], h[v]);
}

// mode 0: top bits -> V1, B1 ; mode 1: mid 11 bits -> V2, G*, Kp
__global__ __launch_bounds__(TPB) void k_find(const unsigned* __restrict__ hist,
                                              unsigned* __restrict__ ws, int mode) {
  __shared__ unsigned part[TPB];
  const int b = blockIdx.x, tid = threadIdx.x;
  const unsigned* h = hist + (size_t)b * NBINS;
  const int per = NBINS / TPB;
  const unsigned Kt = (mode == 0) ? (unsigned)KSEL : (unsigned)KSEL - ws[WS_B1 + b];
  unsigned vals[8];
  unsigned s = 0;
  for (int j = 0; j < per; ++j) { vals[j] = h[tid * per + j]; s += vals[j]; }
  part[tid] = s; __syncthreads();
  for (int off = 1; off < TPB; off <<= 1) {
    unsigned t = (tid >= off) ? part[tid - off] : 0u;
    __syncthreads(); part[tid] += t; __syncthreads();
  }
  unsigned run = part[tid] - s;
  for (int j = 0; j < per; ++j) {
    const unsigned lo = run, c = vals[j];
    run += c;
    if (lo < Kt && Kt <= run) {
      const unsigned v = (unsigned)(tid * per + j);
      if (mode == 0) {
        ws[WS_V1 + b] = v; ws[WS_B1 + b] = lo;
      } else {
        ws[WS_V2 + b] = v;
        const unsigned T22 = (ws[WS_V1 + b] << 11) | v;
        ws[WS_GS + b] = (T22 << 10) | 1023u;        // inclusive 31-bit threshold
        unsigned kp = ws[WS_B1 + b] + lo + c;       // countLess + countEq
        if (kp > (unsigned)KCAP) kp = (unsigned)KCAP;
        ws[WS_KP + b] = kp;
      }
    }
  }
}

// boundary-bin matches with mid <= V2 per range + per channel (L2-resident)
__global__ __launch_bounds__(TPB) void k_cc2(const unsigned* __restrict__ app,
                                             unsigned* __restrict__ ws) {
  __shared__ unsigned lch[3];
  const int b = blockIdx.x, tid = threadIdx.x;
  if (tid < 3) lch[tid] = 0u;
  __syncthreads();
  const unsigned V2 = ws[WS_V2 + b];
  unsigned c0 = 0, c1 = 0, c2 = 0;
  for (int j = 0; j < 3; ++j) {
    const int r = j * 256 + tid;
    const unsigned cnt = ws[WS_RC + b * NRNG + r];
    const unsigned* ap = app + (size_t)b * ACAP + (size_t)r * ASLOT;
    unsigned n2 = 0;
    for (unsigned i = 0; i < cnt; ++i) {
      const unsigned e = ap[i];
      if ((e & 2047u) <= V2) {
        ++n2;
        const unsigned ch = (e >> 11) & 3u;
        if (ch == 0) ++c0; else if (ch == 1) ++c1; else ++c2;
      }
    }
    ws[WS_CNT2 + b * NRNG + r] = n2;
  }
  if (c0) atomicAdd(&lch[0], c0);
  if (c1) atomicAdd(&lch[1], c1);
  if (c2) atomicAdd(&lch[2], c2);
  __syncthreads();
  if (tid < 3 && lch[tid]) atomicAdd(&ws[WS_CHC + b * 4 + tid], lch[tid]);
}

// scan 768 per-range totals (cntLess + cnt2) -> COFF ; channel boundaries
__global__ __launch_bounds__(TPB) void k_cscan(unsigned* __restrict__ ws) {
  __shared__ unsigned wsum[4];
  const int b = blockIdx.x, tid = threadIdx.x;
  const int lane = tid & 63, wv = tid >> 6;
  const unsigned c0 = ws[WS_CNT + b * NRNG + 3 * tid + 0] + ws[WS_CNT2 + b * NRNG + 3 * tid + 0];
  const unsigned c1 = ws[WS_CNT + b * NRNG + 3 * tid + 1] + ws[WS_CNT2 + b * NRNG + 3 * tid + 1];
  const unsigned c2 = ws[WS_CNT + b * NRNG + 3 * tid + 2] + ws[WS_CNT2 + b * NRNG + 3 * tid + 2];
  const unsigned s = c0 + c1 + c2;
  unsigned incl = s;
  for (int off = 1; off < 64; off <<= 1) {
    unsigned t = __shfl_up(incl, off, 64);
    if (lane >= off) incl += t;
  }
  if (lane == 63) wsum[wv] = incl;
  __syncthreads();
  unsigned wpre = 0;
  for (int w = 0; w < wv; ++w) wpre += wsum[w];
  const unsigned excl = incl - s + wpre;
  ws[WS_COFF + b * NRNG + 3 * tid + 0] = excl;
  ws[WS_COFF + b * NRNG + 3 * tid + 1] = excl + c0;
  ws[WS_COFF + b * NRNG + 3 * tid + 2] = excl + c0 + c1;
  if (tid == 0) {
    const unsigned s0 = ws[WS_CHC + b * 4 + 0];
    ws[WS_S0 + b] = s0;
    ws[WS_S01 + b] = s0 + ws[WS_CHC + b * 4 + 1];
  }
}

// Index-ordered compaction -> 4B keys + fused pass-1 hist H0 (+ optional bitmap).
template<int BMP>
__global__ __launch_bounds__(TPB) void k_cscatter(const unsigned* __restrict__ gb,
                                                  const unsigned* __restrict__ ws,
                                                  unsigned* __restrict__ keyArr,
                                                  unsigned* __restrict__ H0,
                                                  unsigned* __restrict__ bmp) {
  __shared__ unsigned h2[256 * NB_S];   // 8 KB
  const int bid = blockIdx.x;
  const int b = bid & 63, blk = bid >> 6, tid = threadIdx.x;
  const int lane = tid & 63, wv = tid >> 6;
  for (int e = tid; e < 256 * NB_S; e += TPB) h2[e] = 0u;
  __syncthreads();
  const unsigned G = ws[WS_GS + b];
  const uint4* g4 = (const uint4*)(gb + (size_t)b * NPS + (size_t)blk * CH_C) + wv * 768;
  unsigned* ka = keyArr + (size_t)b * KCAP;
  unsigned* bw = BMP ? (bmp + (size_t)b * BMPW + (size_t)blk * 384 + (size_t)wv * 96) : nullptr;
  for (int r = 0; r < 3; ++r) {
    unsigned base = ws[WS_COFF + b * NRNG + (blk * 4 + wv) * 3 + r];
#pragma unroll
    for (int it = 0; it < 4; ++it) {
      const uint4 v = g4[r * 256 + it * 64 + lane];
      unsigned k[4] = { v.x & 0x7FFFFFFFu, v.y & 0x7FFFFFFFu, v.z & 0x7FFFFFFFu, v.w & 0x7FFFFFFFu };
      unsigned nib = 0;
      unsigned cnt = 0;
      bool s[4];
#pragma unroll
      for (int c = 0; c < 4; ++c) {
        s[c] = (k[c] <= G);
        nib |= ((unsigned)s[c]) << c;
        cnt += (unsigned)s[c];
      }
      if (BMP) {
        unsigned w = nib << ((lane & 7) * 4);
        w |= __shfl_xor(w, 1, 64);
        w |= __shfl_xor(w, 2, 64);
        w |= __shfl_xor(w, 4, 64);
        if ((lane & 7) == 0) bw[r * 32 + it * 8 + (lane >> 3)] = w;
      }
      unsigned incl = cnt;
      for (int off = 1; off < 64; off <<= 1) {
        unsigned u = __shfl_up(incl, off, 64);
        if (lane >= off) incl += u;
      }
      const unsigned wtot = __shfl(incl, 63, 64);
      unsigned pos = base + incl - cnt;
#pragma unroll
      for (int c = 0; c < 4; ++c) {
        if (s[c]) {
          if (pos < (unsigned)KCAP) {
            ka[pos] = k[c];
            atomicAdd(&h2[(k[c] & 255u) * NB_S + pos / (unsigned)CH_S], 1u);
          }
          ++pos;
        }
      }
      base += wtot;
    }
  }
  __syncthreads();
  unsigned* Hb = H0 + (size_t)b * 256 * NB_S;
  for (int e = tid; e < 256 * NB_S; e += TPB) {
    unsigned c = h2[e];
    if (c) atomicAdd(&Hb[e], c);
  }
}

// per-sample scan of H[b][256][NB_S] counts -> global output bases
__global__ __launch_bounds__(TPB) void k_hscan(unsigned* __restrict__ H) {
  __shared__ unsigned wsum[4];
  const int b = blockIdx.x, tid = threadIdx.x;
  const int lane = tid & 63, wv = tid >> 6;
  unsigned* Hb = H + (size_t)b * 256 * NB_S;
  unsigned row[NB_S];
  unsigned run = 0;
#pragma unroll
  for (int k = 0; k < NB_S; ++k) {
    unsigned t = Hb[tid * NB_S + k];
    row[k] = run; run += t;
  }
  unsigned incl = run;
  for (int off = 1; off < 64; off <<= 1) {
    unsigned t = __shfl_up(incl, off, 64);
    if (lane >= off) incl += t;
  }
  if (lane == 63) wsum[wv] = incl;
  __syncthreads();
  unsigned wpre = 0;
  for (int w = 0; w < wv; ++w) wpre += wsum[w];
  const unsigned excl = incl - run + wpre;
#pragma unroll
  for (int k = 0; k < NB_S; ++k) Hb[tid * NB_S + k] = row[k] + excl;
}

// scan Hf[b][64][NB_S] (49 rows used) -> pairbuf bases; one wave per sample
__global__ __launch_bounds__(64) void k_hscanF(unsigned* __restrict__ Hf) {
  const int b = blockIdx.x, tid = threadIdx.x;
  unsigned* Hb = Hf + (size_t)b * 64 * NB_S;
  unsigned row[NB_S];
  unsigned run = 0;
  if (tid < NFB) {
#pragma unroll
    for (int k = 0; k < NB_S; ++k) {
      unsigned t = Hb[tid * NB_S + k];
      row[k] = run; run += t;
    }
  }
  unsigned incl = run;
  for (int off = 1; off < 64; off <<= 1) {
    unsigned t = __shfl_up(incl, off, 64);
    if (tid >= off) incl += t;
  }
  const unsigned excl = incl - run;
  if (tid < NFB) {
#pragma unroll
    for (int k = 0; k < NB_S; ++k) Hb[tid * NB_S + k] = row[k] + excl;
  }
}

// One stable 8-bit LSD radix pass, TPS=1024 threads, tile=4096 records.
// MODE 0: 4B key array -> records + next hist. MODE 1: records -> records + hist (+Hf).
template<int MODE>
__global__ __launch_bounds__(TPS) void k_sort8(const unsigned* __restrict__ keyIn,
                                               const uint2* __restrict__ inR,
                                               uint2* __restrict__ outR,
                                               const unsigned* __restrict__ Hcur,
                                               unsigned* __restrict__ Hnext,
                                               unsigned* __restrict__ Hf,
                                               const unsigned* __restrict__ ws,
                                               int shift) {
  __shared__ unsigned wh[16][256];
  __shared__ unsigned gout[256];
  __shared__ unsigned gbase[256];
  __shared__ unsigned wsum[4];
  __shared__ uint2    stg[TILE];
  __shared__ unsigned h2[256 * NB_S];
  __shared__ unsigned h2f[(MODE == 1) ? NFB * NB_S : 1];
  const int bid = blockIdx.x;
  const int b = bid & 63, blk = bid >> 6, tid = threadIdx.x;
  const int lane = tid & 63, wv = tid >> 6;
  const unsigned long long ltm = (1ull << lane) - 1ull;
  const unsigned kp = min(ws[WS_KP + b], (unsigned)KCAP);
  const unsigned s0 = (unsigned)blk * CH_S;
  const unsigned s1 = min(s0 + (unsigned)CH_S, kp);
  const unsigned* ki = keyIn + (size_t)b * KCAP;
  const uint2* in = inR + (size_t)b * KCAP;
  uint2* out = outR + (size_t)b * KCAP;
  const bool doF = (MODE == 1) && (Hf != nullptr);

  for (int d = tid; d < 256; d += TPS) gbase[d] = Hcur[((size_t)b * 256 + d) * NB_S + blk];
  for (int e = tid; e < 256 * NB_S; e += TPS) h2[e] = 0u;
  if (MODE == 1) { if (doF) for (int e = tid; e < NFB * NB_S; e += TPS) h2f[e] = 0u; }
  __syncthreads();

  for (unsigned t0 = s0; t0 < s1; t0 += (unsigned)TILE) {
    { uint4* w4 = (uint4*)&wh[0][0];
      w4[tid] = make_uint4(0u, 0u, 0u, 0u); }
    __syncthreads();

    unsigned key[4], cpp[4], wloc[4], dig[4];
    bool val[4];
    const unsigned wbase = t0 + (unsigned)wv * 256u;
#pragma unroll
    for (int c = 0; c < 4; ++c) {
      const unsigned i = wbase + (unsigned)c * 64u + (unsigned)lane;
      val[c] = (i < s1);
      if (MODE == 0) { cpp[c] = i; key[c] = val[c] ? ki[i] : 0u; }
      else { uint2 r = val[c] ? in[i] : make_uint2(0u, 0u); cpp[c] = r.x; key[c] = r.y; }
      dig[c] = (key[c] >> shift) & 255u;
      unsigned long long peers = __ballot(val[c]);
#pragma unroll
      for (int bit = 0; bit < 8; ++bit) {
        unsigned long long bb = __ballot(val[c] && ((dig[c] >> bit) & 1u));
        peers &= ((dig[c] >> bit) & 1u) ? bb : ~bb;
      }
      const unsigned before = (unsigned)__popcll(peers & ltm);
      int ldr = __ffsll((unsigned long long)peers) - 1;
      if (ldr < 0) ldr = 0;
      unsigned old = 0;
      if (val[c] && lane == ldr) old = atomicAdd(&wh[wv][dig[c]], (unsigned)__popcll(peers));
      old = __shfl(old, ldr, 64);
      wloc[c] = old + before;
    }
    __syncthreads();

    unsigned incl = 0, tot = 0;
    if (tid < 256) {
      const unsigned d = (unsigned)tid;
#pragma unroll
      for (int w = 0; w < 16; ++w) tot += wh[w][d];
      incl = tot;
      for (int off = 1; off < 64; off <<= 1) {
        unsigned t = __shfl_up(incl, off, 64);
        if (lane >= off) incl += t;
      }
      if (lane == 63) wsum[wv] = incl;
    }
    __syncthreads();
    if (tid < 256) {
      const unsigned d = (unsigned)tid;
      unsigned wpre = 0;
      for (int w = 0; w < wv; ++w) wpre += wsum[w];
      const unsigned tstart = incl - tot + wpre;
      const unsigned g = gbase[d];
      gout[d] = g - tstart;
      gbase[d] = g + tot;
      unsigned run = tstart;
#pragma unroll
      for (int w = 0; w < 16; ++w) { const unsigned t = wh[w][d]; wh[w][d] = run; run += t; }
    }
    __syncthreads();

#pragma unroll
    for (int c = 0; c < 4; ++c) {
      if (val[c]) {
        uint2 r; r.x = cpp[c]; r.y = key[c];
        stg[wh[wv][dig[c]] + wloc[c]] = r;
      }
    }
    __syncthreads();
    const unsigned nt = min((unsigned)TILE, s1 - t0);
    for (unsigned j = tid; j < nt; j += TPS) {
      const uint2 r = stg[j];
      const unsigned d = (r.y >> shift) & 255u;
      const unsigned pos = gout[d] + j;
      out[pos] = r;
      const unsigned nd = (r.y >> (shift + 8)) & 255u;
      atomicAdd(&h2[nd * NB_S + pos / (unsigned)CH_S], 1u);
      if (doF) atomicAdd(&h2f[(r.x >> 12) * NB_S + pos / (unsigned)CH_S], 1u);
    }
    __syncthreads();
  }

  {
    unsigned* Hb = Hnext + (size_t)b * 256 * NB_S;
    for (int e = tid; e < 256 * NB_S; e += TPS) {
      unsigned c = h2[e];
      if (c) atomicAdd(&Hb[e], c);
    }
    if (doF) {
      unsigned* Hfb = Hf + (size_t)b * 64 * NB_S;
      for (int e = tid; e < NFB * NB_S; e += TPS) {
        unsigned c = h2f[e];
        if (c) atomicAdd(&Hfb[e], c);
      }
    }
  }
}

// Final pass: 7-bit key-digit stable ranking -> exact rank, then bin (cpp, rank)
// by cpp>>12 via LDS atomics (order-free) and write COALESCED pairs.
__global__ __launch_bounds__(TPS) void k_final(const uint2* __restrict__ inR,
                                               uint2* __restrict__ pairOut,
                                               const unsigned* __restrict__ Hcur,
                                               const unsigned* __restrict__ Hf,
                                               const unsigned* __restrict__ ws) {
  __shared__ unsigned wh[16][128];
  __shared__ unsigned gbase[128];
  __shared__ unsigned whF[16][64];
  __shared__ unsigned goutF[64];
  __shared__ unsigned gbaseF[64];
  __shared__ uint2    stg[TILE];
  const int bid = blockIdx.x;
  const int b = bid & 63, blk = bid >> 6, tid = threadIdx.x;
  const int lane = tid & 63, wv = tid >> 6;
  const unsigned long long ltm = (1ull << lane) - 1ull;
  const unsigned kp = min(ws[WS_KP + b], (unsigned)KCAP);
  const unsigned s0 = (unsigned)blk * CH_S;
  const unsigned s1 = min(s0 + (unsigned)CH_S, kp);
  const uint2* in = inR + (size_t)b * KCAP;
  uint2* po = pairOut + (size_t)b * KCAP;

  for (int d = tid; d < 128; d += TPS) gbase[d] = Hcur[((size_t)b * 256 + d) * NB_S + blk];
  for (int d = tid; d < 64; d += TPS)
    gbaseF[d] = (d < NFB) ? Hf[((size_t)b * 64 + d) * NB_S + blk] : 0u;
  __syncthreads();

  for (unsigned t0 = s0; t0 < s1; t0 += (unsigned)TILE) {
    { uint4* p = (uint4*)&wh[0][0];
      if (tid < 512) p[tid] = make_uint4(0u, 0u, 0u, 0u);
      uint4* q = (uint4*)&whF[0][0];
      if (tid >= 512 && tid < 768) q[tid - 512] = make_uint4(0u, 0u, 0u, 0u); }
    __syncthreads();

    unsigned key[4], cpp[4], wloc[4], dig[4];
    bool val[4];
    const unsigned wbase = t0 + (unsigned)wv * 256u;
#pragma unroll
    for (int c = 0; c < 4; ++c) {
      const unsigned i = wbase + (unsigned)c * 64u + (unsigned)lane;
      val[c] = (i < s1);
      uint2 r = val[c] ? in[i] : make_uint2(0u, 0u);
      cpp[c] = r.x; key[c] = r.y;
      dig[c] = (key[c] >> 24) & 127u;
      unsigned long long peers = __ballot(val[c]);
#pragma unroll
      for (int bit = 0; bit < 7; ++bit) {
        unsigned long long bb = __ballot(val[c] && ((dig[c] >> bit) & 1u));
        peers &= ((dig[c] >> bit) & 1u) ? bb : ~bb;
      }
      const unsigned before = (unsigned)__popcll(peers & ltm);
      int ldr = __ffsll((unsigned long long)peers) - 1;
      if (ldr < 0) ldr = 0;
      unsigned old = 0;
      if (val[c] && lane == ldr) old = atomicAdd(&wh[wv][dig[c]], (unsigned)__popcll(peers));
      old = __shfl(old, ldr, 64);
      wloc[c] = old + before;
    }
    __syncthreads();

    if (tid < 128) {
      const unsigned d = (unsigned)tid;
      unsigned run = gbase[d];
#pragma unroll
      for (int w = 0; w < 16; ++w) { const unsigned t = wh[w][d]; wh[w][d] = run; run += t; }
      gbase[d] = run;
    }
    __syncthreads();

    unsigned rnk[4], dbF[4], wlocF[4];
#pragma unroll
    for (int c = 0; c < 4; ++c) {
      dbF[c] = cpp[c] >> 12;
      if (val[c]) {
        rnk[c] = wh[wv][dig[c]] + wloc[c];
        wlocF[c] = atomicAdd(&whF[wv][dbF[c]], 1u);
      }
    }
    __syncthreads();

    if (tid < 64) {
      const unsigned d = (unsigned)tid;
      unsigned tot = 0;
      if (d < NFB) {
#pragma unroll
        for (int w = 0; w < 16; ++w) tot += whF[w][d];
      }
      unsigned incl = tot;
      for (int off = 1; off < 64; off <<= 1) {
        unsigned t = __shfl_up(incl, off, 64);
        if (lane >= off) incl += t;
      }
      const unsigned tstart = incl - tot;
      goutF[d] = gbaseF[d] - tstart;
      gbaseF[d] += tot;
      unsigned run = tstart;
#pragma unroll
      for (int w = 0; w < 16; ++w) { const unsigned t = whF[w][d]; whF[w][d] = run; run += t; }
    }
    __syncthreads();

#pragma unroll
    for (int c = 0; c < 4; ++c) {
      if (val[c]) {
        uint2 r; r.x = cpp[c]; r.y = rnk[c];
        stg[whF[wv][dbF[c]] + wlocF[c]] = r;
      }
    }
    __syncthreads();

    const unsigned nt = min((unsigned)TILE, s1 - t0);
    for (unsigned j = tid; j < nt; j += TPS) {
      const uint2 r = stg[j];
      po[goutF[r.x >> 12] + j] = r;
    }
    __syncthreads();
  }
}

// Unpack: per (sample, fill-bin) block — threefry on dense lanes, LDS scatter,
// write fm linearly.
__global__ __launch_bounds__(TPB) void k_unpack(const uint2* __restrict__ pairs,
                                                unsigned* __restrict__ fm,
                                                const unsigned* __restrict__ ws) {
  __shared__ unsigned vals[4096];
  const int bid = blockIdx.x;
  const int b = bid & 63, d = bid >> 6, tid = threadIdx.x;
  const unsigned kp = min(ws[WS_KP + b], (unsigned)KCAP);
  const unsigned start = (unsigned)d * 4096u;
  if (start >= kp) return;
  const unsigned cnt = min(4096u, kp - start);
  const unsigned S0 = ws[WS_S0 + b], S01 = ws[WS_S01 + b];
  const float* mnf = (const float*)(ws + WS_MN);
  const float* mxf = (const float*)(ws + WS_MX);
  const float l0 = mnf[b * CCH], l1 = mnf[b * CCH + 1], l2 = mnf[b * CCH + 2];
  const float h0 = mxf[b * CCH], h1 = mxf[b * CCH + 1], h2v = mxf[b * CCH + 2];
  const uint2* pb = pairs + (size_t)b * KCAP + start;
  for (unsigned j = tid; j < cnt; j += TPB) {
    const uint2 r = pb[j];
    unsigned res = 0xFFFFFFFFu;
    if (r.y < (unsigned)KSEL) {
      const unsigned p = (unsigned)b * (unsigned)KSEL + r.y;
      unsigned o0, o1;
      threefry2x32(0u, 42u, 0u, p, o0, o1);
      const unsigned bits = o0 ^ o1;
      const float u = __uint_as_float((bits >> 9) | 0x3f800000u) - 1.0f;
      const unsigned ch = (unsigned)(r.x >= S0) + (unsigned)(r.x >= S01);
      const float lo = (ch == 0) ? l0 : ((ch == 1) ? l1 : l2);
      const float hi = (ch == 0) ? h0 : ((ch == 1) ? h1 : h2v);
      res = __float_as_uint(lo + u * (hi - lo));
    }
    vals[r.x & 4095u] = res;
  }
  __syncthreads();
  unsigned* f = fm + (size_t)b * KCAP + start;
  for (unsigned j = tid; j < cnt; j += TPB) f[j] = vals[j];
}

// Fused copy+fill. BMP=1: predicate from select-bitmap (no grad read).
template<int BMP>
__global__ __launch_bounds__(TPB) void k_fill(const u32x4* __restrict__ x4,
                                              const u32x4* __restrict__ g4all,
                                              const unsigned* __restrict__ bmp,
                                              const unsigned* __restrict__ fillmap,
                                              const unsigned* __restrict__ ws,
                                              u32x4* __restrict__ out4) {
  const int bid = blockIdx.x;
  const int b = bid & 63, blk = bid >> 6, tid = threadIdx.x;
  const int lane = tid & 63, wv = tid >> 6;
  const unsigned G = ws[WS_GS + b];
  const unsigned kp = min(ws[WS_KP + b], (unsigned)KCAP);
  const size_t t4 = (size_t)b * (NPS / 4) + (size_t)blk * (CH_C / 4) + (size_t)wv * 768;
  const unsigned* fm = fillmap + (size_t)b * KCAP;
  const unsigned* bw = BMP ? (bmp + (size_t)b * BMPW + (size_t)blk * 384 + (size_t)wv * 96) : nullptr;
  for (int r = 0; r < 3; ++r) {
    unsigned base = ws[WS_COFF + b * NRNG + (blk * 4 + wv) * 3 + r];
#pragma unroll
    for (int it = 0; it < 4; ++it) {
      const size_t a = t4 + r * 256 + it * 64 + lane;
      u32x4 xv = __builtin_nontemporal_load(&x4[a]);
      unsigned nib;
      if (BMP) {
        const unsigned w = bw[r * 32 + it * 8 + (lane >> 3)];
        nib = (w >> ((lane & 7) * 4)) & 0xFu;
      } else {
        const u32x4 gv = __builtin_nontemporal_load(&g4all[a]);
        nib = (unsigned)((gv.x & 0x7FFFFFFFu) <= G)
            | ((unsigned)((gv.y & 0x7FFFFFFFu) <= G) << 1)
            | ((unsigned)((gv.z & 0x7FFFFFFFu) <= G) << 2)
            | ((unsigned)((gv.w & 0x7FFFFFFFu) <= G) << 3);
      }
      const unsigned cnt = (unsigned)__popc(nib);
      unsigned incl = cnt;
      for (int off = 1; off < 64; off <<= 1) {
        unsigned u = __shfl_up(incl, off, 64);
        if (lane >= off) incl += u;
      }
      const unsigned wtot = __shfl(incl, 63, 64);
      unsigned pos = base + incl - cnt;
#pragma unroll
      for (int c = 0; c < 4; ++c) {
        if ((nib >> c) & 1u) {
          if (pos < kp) {
            const unsigned rr = fm[pos];
            if (rr != 0xFFFFFFFFu) xv[c] = rr;
          }
          ++pos;
        }
      }
      __builtin_nontemporal_store(xv, &out4[a]);
      base += wtot;
    }
  }
}

extern "C" void kernel_launch(void* const* d_in, const int* in_sizes, int n_in,
                              void* d_out, int out_size, void* d_ws, size_t ws_size,
                              hipStream_t stream) {
  const float* x = (const float*)d_in[0];
  const unsigned* gb = (const unsigned*)d_in[1];   // grad bits
  float* out = (float*)d_out;
  unsigned* ws = (unsigned*)d_ws;
  if (ws_size < WS_NEEDED_BYTES) return;
  const bool useBmp = (ws_size >= WS_NEEDED_BMP);

  unsigned* R1 = ws + WS_FIX_END;                  // keys / records / pairs
  unsigned* R2 = ws + WS_FIX_END + RECW;           // append scratch / records / fm
  unsigned* BMP = ws + WS_BMP_OFF;                 // select-bitmap (optional)
  unsigned* H0 = ws + WS_H0;
  unsigned* H1 = ws + WS_H1;
  unsigned* H2 = ws + WS_H2;
  unsigned* H3 = ws + WS_H3;
  unsigned* HF = ws + WS_HF;

  dim3 blk(TPB);
  dim3 sblk(TPS);

  // 0. min/max partials ; zero atomically-accumulated region (CHC..FIX_END)
  k_mnmx<<<dim3(BN * CCH * SUB), blk, 0, stream>>>((const float4*)x, ws);
  k_mnfin<<<dim3(1), blk, 0, stream>>>(ws);
  {
    const int nz = (int)(WS_FIX_END - WS_CHC);
    k_zero<<<dim3((nz + TPB - 1) / TPB), blk, 0, stream>>>(ws + WS_CHC, nz);
  }

  // 1. threshold refinement: thrA ; fused thrB+rangecount (segmented append) ; cc2
  k_thrA<<<dim3(NB_T, BN), blk, 0, stream>>>(gb, ws + WS_THA);
  k_find<<<dim3(BN), blk, 0, stream>>>(ws + WS_THA, ws, 0);
  k_thrBC<<<dim3(NB_C * BN), blk, 0, stream>>>(gb, ws + WS_THB, R2, ws);
  k_find<<<dim3(BN), blk, 0, stream>>>(ws + WS_THB, ws, 1);
  k_cc2<<<dim3(BN), blk, 0, stream>>>(R2, ws);
  k_cscan<<<dim3(BN), blk, 0, stream>>>(ws);

  // 2. index-ordered compaction (4B keys) + fused pass-1 histogram (+ bitmap)
  if (useBmp) k_cscatter<1><<<dim3(NB_C * BN), blk, 0, stream>>>(gb, ws, R1, H0, BMP);
  else        k_cscatter<0><<<dim3(NB_C * BN), blk, 0, stream>>>(gb, ws, R1, H0, nullptr);

  // 3. stable LSD radix sort on keys (8/8/8), pass 3 also builds fill-bin hist HF
  k_hscan<<<dim3(BN), blk, 0, stream>>>(H0);
  k_sort8<0><<<dim3(NB_S * BN), sblk, 0, stream>>>(R1, (const uint2*)nullptr, (uint2*)R2, H0, H1, nullptr, ws, 0);
  k_hscan<<<dim3(BN), blk, 0, stream>>>(H1);
  k_sort8<1><<<dim3(NB_S * BN), sblk, 0, stream>>>(nullptr, (const uint2*)R2, (uint2*)R1, H1, H2, nullptr, ws, 8);
  k_hscan<<<dim3(BN), blk, 0, stream>>>(H2);
  k_sort8<1><<<dim3(NB_S * BN), sblk, 0, stream>>>(nullptr, (const uint2*)R1, (uint2*)R2, H2, H3, HF, ws, 16);
  k_hscan<<<dim3(BN), blk, 0, stream>>>(H3);
  k_hscanF<<<dim3(BN), dim3(64), 0, stream>>>(HF);

  // 4. final: rank + binned coalesced (cpp,rank) pairs ; unpack (threefry) -> fm
  k_final<<<dim3(NB_S * BN), sblk, 0, stream>>>((const uint2*)R2, (uint2*)R1, H3, HF, ws);
  k_unpack<<<dim3(NFB * BN), blk, 0, stream>>>((const uint2*)R1, R2, ws);

  // 5. fused copy + fill (pure streaming; bitmap path skips grad entirely)
  if (useBmp) k_fill<1><<<dim3(NB_C * BN), blk, 0, stream>>>((const u32x4*)x, nullptr, BMP, R2, ws, (u32x4*)out);
  else        k_fill<0><<<dim3(NB_C * BN), blk, 0, stream>>>((const u32x4*)x, (const u32x4*)gb, nullptr, R2, ws, (u32x4*)out);
}